// Round 3
// baseline (10786.060 us; speedup 1.0000x reference)
//
#include <hip/hip_runtime.h>
#include <math.h>

#define CH    64
#define WW    192
#define HH    192
#define HWSZ  (192*192)
#define KK    49
#define ROWP  68   // padded LDS row: 68%32=4 banks stride -> 2-way (free)

// ---------------------------------------------------------------------------
// k_prep: build (a) circular-conv kernels kr from fft_w, (b) k-major deform
// weights wT[k][o][c], (c) tap-major 3x3 weights w2T[tap][o][c].
// ---------------------------------------------------------------------------
__device__ const float c_cos8[8] = {
    1.f, 0.70710678118654752f, 0.f, -0.70710678118654752f,
   -1.f, -0.70710678118654752f, 0.f, 0.70710678118654752f };

__global__ void k_prep(const float* __restrict__ fw,   // [64,1,1,8,5]
                       const float* __restrict__ wd,   // [64,64,7,7]
                       const float* __restrict__ w2,   // [64,64,3,3]
                       float* __restrict__ krT,        // [64 uv][64 c]
                       float* __restrict__ wT,         // [49][64 o][64 c]
                       float* __restrict__ w2T)        // [9][64 o][64 c]
{
    int tid = blockIdx.x * blockDim.x + threadIdx.x;
    int nt  = gridDim.x * blockDim.x;
    for (int t = tid; t < 64 * 64; t += nt) {
        int uv = t >> 6, c = t & 63;
        int u = uv >> 3, v = uv & 7;
        float acc = 0.f;
        for (int ky = 0; ky < 8; ky++)
            for (int kx = 0; kx < 8; kx++) {
                float wv = (kx <= 4) ? fw[c * 40 + ky * 5 + kx]
                                     : fw[c * 40 + ((8 - ky) & 7) * 5 + (8 - kx)];
                acc += wv * c_cos8[(ky * u + kx * v) & 7];
            }
        krT[uv * 64 + c] = acc * (1.f / 64.f);
    }
    for (int t = tid; t < KK * 4096; t += nt) {
        int k = t / 4096, rem = t & 4095;
        int o = rem >> 6, c = rem & 63;
        wT[t] = wd[(o * 64 + c) * KK + k];
    }
    for (int t = tid; t < 9 * 4096; t += nt) {
        int tap = t / 4096, rem = t & 4095;
        int o = rem >> 6, c = rem & 63;
        w2T[t] = w2[(o * 64 + c) * 9 + tap];
    }
}

// ---------------------------------------------------------------------------
// k_trans: enc [c][p] -> encP [p][c]  (pixel-major for coalesced sampling)
// ---------------------------------------------------------------------------
__global__ __launch_bounds__(256) void k_trans(
    const float* __restrict__ enc, float* __restrict__ encP)
{
    __shared__ float s[64 * 65];
    int t = threadIdx.x;
    int base = blockIdx.x * 64;
#pragma unroll
    for (int r = 0; r < 16; r++) {
        int idx = t + r * 256;
        int p = idx & 63, c = idx >> 6;
        s[p * 65 + c] = enc[c * HWSZ + base + p];
    }
    __syncthreads();
#pragma unroll
    for (int r = 0; r < 16; r++) {
        int idx = t + r * 256;
        int c = idx & 63, p = idx >> 6;
        encP[(base + p) * 64 + c] = s[p * 65 + c];
    }
}

// ---------------------------------------------------------------------------
// k_deform: modulated deformable conv v2 (7x7, pad 3) fused with 1x1 w_conv1.
// Software-pipelined K-loop:
//   offsets/mask prefetched 2 taps ahead (register slots, no deps)
//   corner loads + weight loads issued 1 tap ahead at iteration top
//   blend + LDS commit after GEMM (post-B1) -> global latency hidden by GEMM
// Two barriers per tap; neither waits on global loads.
// ---------------------------------------------------------------------------
__global__ __launch_bounds__(256, 2) void k_deform(
    const float* __restrict__ encP, const float* __restrict__ off,
    const float* __restrict__ msk, const float* __restrict__ wT,
    const float* __restrict__ wc1, float* __restrict__ rev)
{
    __shared__ __align__(16) float s[64 * ROWP];   // samples [px][c]
    __shared__ __align__(16) float wk[64 * ROWP];  // weights [o][c]; reused as d[px][o]

    int t = threadIdx.x;
    int bx = blockIdx.x % 12, by = blockIdx.x / 12;
    int gx0 = bx * 16, gy0 = by * 4;

    // sampling role: quarter-wave per sample point; 16 lanes x float4 = 64 ch
    int lane = t & 63;
    int wv_i = t >> 6;
    int q    = lane >> 4;
    int cc   = (lane & 15) * 4;

    // compute role
    int ot  = (t >> 4) * 4;
    int pxl = t & 15;

    // weight staging role
    int so  = t >> 4;
    int scc = (t & 15) * 4;

    int spx[4], sgp[4], sgx[4], sgy[4];
#pragma unroll
    for (int i = 0; i < 4; i++) {
        int px = wv_i * 16 + i * 4 + q;
        spx[i] = px;
        sgy[i] = gy0 + (px >> 4);
        sgx[i] = gx0 + (px & 15);
        sgp[i] = sgy[i] * WW + sgx[i];
    }

    float  ody[2][4], odx[2][4], om[2][4];   // offset/mask slots (2 taps deep)
    float4 c00[4], c01[4], c10[4], c11[4];   // in-flight bilinear corners
    float  a00[4], a01[4], a10[4], a11[4];   // blend weights * mask
    float4 rw[4];                            // in-flight weight tile

    auto load_off = [&](int k, int slot) {
        const float* offY = off + 2 * k * HWSZ;
        const float* offX = offY + HWSZ;
        const float* mk   = msk + k * HWSZ;
#pragma unroll
        for (int i = 0; i < 4; i++) {
            ody[slot][i] = offY[sgp[i]];
            odx[slot][i] = offX[sgp[i]];
            om [slot][i] = mk  [sgp[i]];
        }
    };

    auto issue = [&](int k, int slot) {
        int ky = k / 7, kx = k % 7;
#pragma unroll
        for (int i = 0; i < 4; i++) {
            float y = (float)(sgy[i] - 3 + ky) + ody[slot][i];
            float x = (float)(sgx[i] - 3 + kx) + odx[slot][i];
            float m = om[slot][i];
            float y0f = floorf(y), x0f = floorf(x);
            float wy = y - y0f, wx = x - x0f;
            int iy0 = (int)y0f, ix0 = (int)x0f;
            bool vy0 = (iy0 >=  0) & (iy0 < HH);
            bool vy1 = (iy0 >= -1) & (iy0 < HH - 1);
            bool vx0 = (ix0 >=  0) & (ix0 < WW);
            bool vx1 = (ix0 >= -1) & (ix0 < WW - 1);
            const float4 z4 = make_float4(0.f, 0.f, 0.f, 0.f);
            const float* b00 = encP + (iy0 * WW + ix0) * 64 + cc;
            c00[i] = (vy0 & vx0) ? *(const float4*)(b00)                : z4;
            c01[i] = (vy0 & vx1) ? *(const float4*)(b00 + 64)           : z4;
            c10[i] = (vy1 & vx0) ? *(const float4*)(b00 + WW * 64)      : z4;
            c11[i] = (vy1 & vx1) ? *(const float4*)(b00 + WW * 64 + 64) : z4;
            a00[i] = (1.f - wy) * (1.f - wx) * m;
            a01[i] = (1.f - wy) * wx * m;
            a10[i] = wy * (1.f - wx) * m;
            a11[i] = wy * wx * m;
        }
#pragma unroll
        for (int r = 0; r < 4; r++) {
            int o = so + r * 16;
            rw[r] = *(const float4*)&wT[k * 4096 + o * 64 + scc];
        }
    };

    auto commit = [&]() {
#pragma unroll
        for (int i = 0; i < 4; i++) {
            float4 v;
            v.x = a00[i]*c00[i].x + a01[i]*c01[i].x + a10[i]*c10[i].x + a11[i]*c11[i].x;
            v.y = a00[i]*c00[i].y + a01[i]*c01[i].y + a10[i]*c10[i].y + a11[i]*c11[i].y;
            v.z = a00[i]*c00[i].z + a01[i]*c01[i].z + a10[i]*c10[i].z + a11[i]*c11[i].z;
            v.w = a00[i]*c00[i].w + a01[i]*c01[i].w + a10[i]*c10[i].w + a11[i]*c11[i].w;
            *(float4*)&s[spx[i] * ROWP + cc] = v;
        }
#pragma unroll
        for (int r = 0; r < 4; r++) {
            int o = so + r * 16;
            *(float4*)&wk[o * ROWP + scc] = rw[r];
        }
    };

    // prime the pipeline: off(0), off(1); corners+weights(0); commit(0)
    load_off(0, 0);
    load_off(1, 1);
    issue(0, 0);
    commit();
    __syncthreads();

    float acc[4][4];
#pragma unroll
    for (int i = 0; i < 4; i++)
#pragma unroll
        for (int j = 0; j < 4; j++) acc[i][j] = 0.f;

    for (int k = 0; k < KK; k++) {
        if (k + 2 < KK) load_off(k + 2, k & 1);
        if (k + 1 < KK) issue(k + 1, (k + 1) & 1);
        // GEMM on tap k: acc[i][j] += sum_c wk[ot+i][c] * s[pxl+16j][c]
#pragma unroll
        for (int c4 = 0; c4 < 16; c4++) {
            float4 wv4[4], sv[4];
#pragma unroll
            for (int i = 0; i < 4; i++)
                wv4[i] = *(const float4*)&wk[(ot + i) * ROWP + c4 * 4];
#pragma unroll
            for (int j = 0; j < 4; j++)
                sv[j] = *(const float4*)&s[(pxl + 16 * j) * ROWP + c4 * 4];
#pragma unroll
            for (int i = 0; i < 4; i++)
#pragma unroll
                for (int j = 0; j < 4; j++)
                    acc[i][j] += wv4[i].x * sv[j].x + wv4[i].y * sv[j].y
                               + wv4[i].z * sv[j].z + wv4[i].w * sv[j].w;
        }
        __syncthreads();              // B1: all waves done reading s, wk
        if (k + 1 < KK) commit();     // blend (corner waitcnt lands here) + write
        __syncthreads();              // B2: writes visible
    }

    // epilogue: d[px][o] into wk (reused)
#pragma unroll
    for (int j = 0; j < 4; j++) {
        float4 dv = make_float4(acc[0][j], acc[1][j], acc[2][j], acc[3][j]);
        *(float4*)&wk[(pxl + 16 * j) * ROWP + ot] = dv;
    }
    __syncthreads();

    // fused 1x1 conv: rev[px][o2] = sum_o wc1[o2][o] * d[px][o]
    float a2[4][4];
#pragma unroll
    for (int i = 0; i < 4; i++)
#pragma unroll
        for (int j = 0; j < 4; j++) a2[i][j] = 0.f;
#pragma unroll
    for (int c4 = 0; c4 < 16; c4++) {
        float4 wv4[4], sv[4];
#pragma unroll
        for (int i = 0; i < 4; i++)
            wv4[i] = *(const float4*)&wc1[(ot + i) * 64 + c4 * 4];
#pragma unroll
        for (int j = 0; j < 4; j++)
            sv[j] = *(const float4*)&wk[(pxl + 16 * j) * ROWP + c4 * 4];
#pragma unroll
        for (int i = 0; i < 4; i++)
#pragma unroll
            for (int j = 0; j < 4; j++)
                a2[i][j] += wv4[i].x * sv[j].x + wv4[i].y * sv[j].y
                          + wv4[i].z * sv[j].z + wv4[i].w * sv[j].w;
    }
#pragma unroll
    for (int j = 0; j < 4; j++) {
        int gp = (gy0 + j) * WW + gx0 + pxl;
        float4 rv = make_float4(a2[0][j], a2[1][j], a2[2][j], a2[3][j]);
        *(float4*)&rev[gp * 64 + ot] = rv;
    }
}

// ---------------------------------------------------------------------------
// k_fft: per 8x8 patch: e0 = w_proj_in @ enc (1x1 conv), then per-channel
// circular conv with kr.  Stages from pixel-major encP (coalesced float4).
// ---------------------------------------------------------------------------
__global__ __launch_bounds__(256) void k_fft(
    const float* __restrict__ encPg, const float* __restrict__ wpi,
    const float* __restrict__ krT, float* __restrict__ e1)
{
    __shared__ __align__(16) float encP[64 * ROWP];  // [px][c]
    __shared__ __align__(16) float e0[64 * ROWP];    // [px][o]
    int t = threadIdx.x;
    int pbx = blockIdx.x % 24, pby = blockIdx.x / 24;
    int gx0 = pbx * 8, gy0 = pby * 8;

#pragma unroll
    for (int r = 0; r < 4; r++) {
        int idx = t + r * 256;
        int px = idx >> 4, cg = (idx & 15) * 4;
        int gy = gy0 + (px >> 3), gx = gx0 + (px & 7);
        *(float4*)&encP[px * ROWP + cg] =
            *(const float4*)&encPg[(gy * WW + gx) * 64 + cg];
    }
    __syncthreads();

    // proj_in matvec: e0[px][o] = sum_c wpi[o][c] * encP[px][c]
    int ot = (t >> 4) * 4, pxl = t & 15;
    float acc[4][4];
#pragma unroll
    for (int i = 0; i < 4; i++)
#pragma unroll
        for (int j = 0; j < 4; j++) acc[i][j] = 0.f;
#pragma unroll
    for (int c4 = 0; c4 < 16; c4++) {
        float4 wv4[4], sv[4];
#pragma unroll
        for (int i = 0; i < 4; i++)
            wv4[i] = *(const float4*)&wpi[(ot + i) * 64 + c4 * 4];
#pragma unroll
        for (int j = 0; j < 4; j++)
            sv[j] = *(const float4*)&encP[(pxl + 16 * j) * ROWP + c4 * 4];
#pragma unroll
        for (int i = 0; i < 4; i++)
#pragma unroll
            for (int j = 0; j < 4; j++)
                acc[i][j] += wv4[i].x * sv[j].x + wv4[i].y * sv[j].y
                           + wv4[i].z * sv[j].z + wv4[i].w * sv[j].w;
    }
#pragma unroll
    for (int j = 0; j < 4; j++) {
        float4 dv = make_float4(acc[0][j], acc[1][j], acc[2][j], acc[3][j]);
        *(float4*)&e0[(pxl + 16 * j) * ROWP + ot] = dv;
    }
    __syncthreads();

    // circular conv: out[y][x] = sum_{u,v} kr[u][v] * e0[(y-u)%8][(x-v)%8]
    int o = t & 63;
    int yb = t >> 6;
#pragma unroll
    for (int yy = 0; yy < 2; yy++) {
        int y = yb + yy * 4;
        float outr[8];
#pragma unroll
        for (int x = 0; x < 8; x++) outr[x] = 0.f;
#pragma unroll
        for (int u = 0; u < 8; u++) {
            int ry = (y - u + 8) & 7;
            float row[8];
#pragma unroll
            for (int rx = 0; rx < 8; rx++)
                row[rx] = e0[(ry * 8 + rx) * ROWP + o];
#pragma unroll
            for (int v = 0; v < 8; v++) {
                float kv = krT[(u * 8 + v) * 64 + o];
#pragma unroll
                for (int x = 0; x < 8; x++)
                    outr[x] += kv * row[(x - v + 8) & 7];
            }
        }
        int gy = gy0 + y;
#pragma unroll
        for (int x = 0; x < 8; x++)
            e1[(gy * WW + gx0 + x) * 64 + o] = outr[x];
    }
}

// ---------------------------------------------------------------------------
// k_conv3: e3 = conv3x3(e1 + rev, w_conv2, pad 1).  Block = 16x4 tile + halo.
// ---------------------------------------------------------------------------
__global__ __launch_bounds__(256) void k_conv3(
    const float* __restrict__ e1, const float* __restrict__ rev,
    const float* __restrict__ w2T, float* __restrict__ e3)
{
    __shared__ __align__(16) float tl[108 * ROWP];   // halo tile 18x6 [hp][c]
    int t = threadIdx.x;
    int bx = blockIdx.x % 12, by = blockIdx.x / 12;
    int gx0 = bx * 16, gy0 = by * 4;

#pragma unroll
    for (int r = 0; r < 27; r++) {
        int idx = t + r * 256;
        int c = idx & 63, hp = idx >> 6;
        int hy = hp / 18, hx = hp % 18;
        int gy = gy0 + hy - 1, gx = gx0 + hx - 1;
        float v = 0.f;
        if (gy >= 0 && gy < HH && gx >= 0 && gx < WW) {
            int gp = gy * WW + gx;
            v = e1[gp * 64 + c] + rev[gp * 64 + c];
        }
        tl[hp * ROWP + c] = v;
    }
    __syncthreads();

    int ot = (t >> 4) * 4, pxl = t & 15;
    float acc[4][4];
#pragma unroll
    for (int i = 0; i < 4; i++)
#pragma unroll
        for (int j = 0; j < 4; j++) acc[i][j] = 0.f;

    for (int tap = 0; tap < 9; tap++) {
        int dy = tap / 3, dx = tap % 3;
        const float* wt = w2T + tap * 4096;
#pragma unroll
        for (int c4 = 0; c4 < 16; c4++) {
            float4 wv4[4], sv[4];
#pragma unroll
            for (int i = 0; i < 4; i++)
                wv4[i] = *(const float4*)&wt[(ot + i) * 64 + c4 * 4];
#pragma unroll
            for (int j = 0; j < 4; j++) {
                int hp = (j + dy) * 18 + (pxl + dx);
                sv[j] = *(const float4*)&tl[hp * ROWP + c4 * 4];
            }
#pragma unroll
            for (int i = 0; i < 4; i++)
#pragma unroll
                for (int j = 0; j < 4; j++)
                    acc[i][j] += wv4[i].x * sv[j].x + wv4[i].y * sv[j].y
                               + wv4[i].z * sv[j].z + wv4[i].w * sv[j].w;
        }
    }
#pragma unroll
    for (int j = 0; j < 4; j++) {
        int gp = (gy0 + j) * WW + gx0 + pxl;
        float4 rv = make_float4(acc[0][j], acc[1][j], acc[2][j], acc[3][j]);
        *(float4*)&e3[gp * 64 + ot] = rv;
    }
}

// ---------------------------------------------------------------------------
// k_out: feat = [e3 ; dec], g = w_proj_out @ feat (128->128),
// out[o] = g[o] * g[o+64].
// ---------------------------------------------------------------------------
#define ROWF 132

__global__ __launch_bounds__(256) void k_out(
    const float* __restrict__ e3, const float* __restrict__ dec,
    const float* __restrict__ wpo, float* __restrict__ out)
{
    __shared__ __align__(16) float f[64 * ROWF];
    int t = threadIdx.x;
    int bx = blockIdx.x % 12, by = blockIdx.x / 12;
    int gx0 = bx * 16, gy0 = by * 4;

#pragma unroll
    for (int r = 0; r < 16; r++) {
        int idx = t + r * 256;
        int c = idx & 63, px = idx >> 6;
        int gp = (gy0 + (px >> 4)) * WW + gx0 + (px & 15);
        f[px * ROWF + c] = e3[gp * 64 + c];
    }
#pragma unroll
    for (int r = 0; r < 16; r++) {
        int idx = t + r * 256;
        int px = idx & 63, c = idx >> 6;
        int gp = (gy0 + (px >> 4)) * WW + gx0 + (px & 15);
        f[px * ROWF + 64 + c] = dec[c * HWSZ + gp];
    }
    __syncthreads();

    int ot = (t >> 4) * 4, pxl = t & 15;
    float a1[4][4], a2[4][4];
#pragma unroll
    for (int i = 0; i < 4; i++)
#pragma unroll
        for (int j = 0; j < 4; j++) { a1[i][j] = 0.f; a2[i][j] = 0.f; }

#pragma unroll
    for (int c4 = 0; c4 < 32; c4++) {
        float4 w1[4], w2[4], sv[4];
#pragma unroll
        for (int i = 0; i < 4; i++) {
            w1[i] = *(const float4*)&wpo[(ot + i) * 128 + c4 * 4];
            w2[i] = *(const float4*)&wpo[(ot + i + 64) * 128 + c4 * 4];
        }
#pragma unroll
        for (int j = 0; j < 4; j++)
            sv[j] = *(const float4*)&f[(pxl + 16 * j) * ROWF + c4 * 4];
#pragma unroll
        for (int i = 0; i < 4; i++)
#pragma unroll
            for (int j = 0; j < 4; j++) {
                a1[i][j] += w1[i].x * sv[j].x + w1[i].y * sv[j].y
                          + w1[i].z * sv[j].z + w1[i].w * sv[j].w;
                a2[i][j] += w2[i].x * sv[j].x + w2[i].y * sv[j].y
                          + w2[i].z * sv[j].z + w2[i].w * sv[j].w;
            }
    }
#pragma unroll
    for (int j = 0; j < 4; j++) {
        int gp = (gy0 + j) * WW + gx0 + pxl;
#pragma unroll
        for (int i = 0; i < 4; i++)
            out[(ot + i) * HWSZ + gp] = a1[i][j] * a2[i][j];
    }
}

// ---------------------------------------------------------------------------
extern "C" void kernel_launch(void* const* d_in, const int* in_sizes, int n_in,
                              void* d_out, int out_size, void* d_ws, size_t ws_size,
                              hipStream_t stream)
{
    const float* enc  = (const float*)d_in[0];
    const float* dec  = (const float*)d_in[1];
    const float* ioff = (const float*)d_in[2];
    const float* iwt  = (const float*)d_in[3];
    const float* wpi  = (const float*)d_in[4];
    const float* fw   = (const float*)d_in[5];
    const float* wpo  = (const float*)d_in[6];
    const float* wd   = (const float*)d_in[7];
    const float* wc1  = (const float*)d_in[8];
    const float* wc2  = (const float*)d_in[9];
    float* out = (float*)d_out;
    float* ws  = (float*)d_ws;

    float* krT  = ws;                 //   4096
    float* wT   = ws + 4096;          // 200704
    float* w2T  = ws + 204800;        //  36864
    float* rev  = ws + 241664;        // 2359296  [px][64]
    float* e1   = ws + 2600960;       // 2359296  [px][64]
    float* e3   = ws + 4960256;       // 2359296  [px][64]
    float* encP = ws + 7319552;       // 2359296  [px][64]

    hipLaunchKernelGGL(k_prep,   dim3(256), dim3(256), 0, stream, fw, wd, wc2, krT, wT, w2T);
    hipLaunchKernelGGL(k_trans,  dim3(576), dim3(256), 0, stream, enc, encP);
    hipLaunchKernelGGL(k_deform, dim3(576), dim3(256), 0, stream, encP, ioff, iwt, wT, wc1, rev);
    hipLaunchKernelGGL(k_fft,    dim3(576), dim3(256), 0, stream, encP, wpi, krT, e1);
    hipLaunchKernelGGL(k_conv3,  dim3(576), dim3(256), 0, stream, e1, rev, w2T, e3);
    hipLaunchKernelGGL(k_out,    dim3(576), dim3(256), 0, stream, e3, dec, wpo, out);
}

// Round 4
// 707.472 us; speedup vs baseline: 15.2459x; 15.2459x over previous
//
#include <hip/hip_runtime.h>
#include <math.h>

#define CH    64
#define WW    192
#define HH    192
#define HWSZ  (192*192)
#define KK    49
#define ROWP  68   // padded LDS row (fp32 kernels)
#define SROW  72   // bf16 sample row stride (shorts): 144B, 16B-multiple

typedef __attribute__((ext_vector_type(8))) short s16x8;   // 8 bf16 = 4 VGPR
typedef __attribute__((ext_vector_type(4))) float f32x4;

__device__ __forceinline__ unsigned short f2bf(float f) {
    union { float f; unsigned u; } v; v.f = f;
    unsigned u = v.u + 0x7FFFu + ((v.u >> 16) & 1u);   // RNE
    return (unsigned short)(u >> 16);
}

// ---------------------------------------------------------------------------
// k_prep (grid 49 x 256):
//  - krT: circular-conv kernels from fft_w (grid-stride)
//  - w2T: tap-major 3x3 weights (grid-stride)
//  - fold: wfold[k][o2][c] = sum_o wc1[o2][o] * wd[o][c][k]  (block per k)
//    packed bf16 in MFMA A-fragment lane order:
//    wA[(k*8 + otile*2 + kt)*512 + lane*8 + j],
//    lane = q*16 + (o2&15), q=(c>>3)&3, kt=c>>5, j=c&7   [A[m][k=q*8+j], m120]
// ---------------------------------------------------------------------------
__device__ const float c_cos8[8] = {
    1.f, 0.70710678118654752f, 0.f, -0.70710678118654752f,
   -1.f, -0.70710678118654752f, 0.f, 0.70710678118654752f };

__global__ __launch_bounds__(256) void k_prep(
    const float* __restrict__ fw,   // [64,1,1,8,5]
    const float* __restrict__ wd,   // [64,64,7,7]
    const float* __restrict__ w2,   // [64,64,3,3]
    const float* __restrict__ wc1,  // [64,64,1,1]
    float* __restrict__ krT,        // [64 uv][64 c]
    float* __restrict__ w2T,        // [9][64 o][64 c]
    short* __restrict__ wA)         // packed bf16 A-fragments [49*8*512]
{
    int tid = blockIdx.x * blockDim.x + threadIdx.x;
    int nt  = gridDim.x * blockDim.x;
    for (int t = tid; t < 64 * 64; t += nt) {
        int uv = t >> 6, c = t & 63;
        int u = uv >> 3, v = uv & 7;
        float acc = 0.f;
        for (int ky = 0; ky < 8; ky++)
            for (int kx = 0; kx < 8; kx++) {
                float wv = (kx <= 4) ? fw[c * 40 + ky * 5 + kx]
                                     : fw[c * 40 + ((8 - ky) & 7) * 5 + (8 - kx)];
                acc += wv * c_cos8[(ky * u + kx * v) & 7];
            }
        krT[uv * 64 + c] = acc * (1.f / 64.f);
    }
    for (int t = tid; t < 9 * 4096; t += nt) {
        int tap = t / 4096, rem = t & 4095;
        int o = rem >> 6, c = rem & 63;
        w2T[t] = w2[(o * 64 + c) * 9 + tap];
    }

    // ---- fold + pack: one block per tap k ----
    __shared__ float wdk [64 * ROWP];
    __shared__ float wc1s[64 * ROWP];
    int k = blockIdx.x;
    int t = threadIdx.x;
#pragma unroll
    for (int r = 0; r < 16; r++) {
        int idx = t + r * 256;
        int o = idx >> 6, c = idx & 63;
        wdk [o * ROWP + c] = wd[(o * 64 + c) * KK + k];
        wc1s[o * ROWP + c] = wc1[o * 64 + c];
    }
    __syncthreads();

    int ot = (t >> 4) * 4, cb = (t & 15) * 4;
    float a[4][4];
#pragma unroll
    for (int i = 0; i < 4; i++)
#pragma unroll
        for (int j = 0; j < 4; j++) a[i][j] = 0.f;
    for (int o = 0; o < 64; o++) {
        float wv_[4], sv_[4];
#pragma unroll
        for (int i = 0; i < 4; i++) wv_[i] = wc1s[(ot + i) * ROWP + o];
#pragma unroll
        for (int j = 0; j < 4; j++) sv_[j] = wdk[o * ROWP + cb + j];
#pragma unroll
        for (int i = 0; i < 4; i++)
#pragma unroll
            for (int j = 0; j < 4; j++) a[i][j] += wv_[i] * sv_[j];
    }
#pragma unroll
    for (int i = 0; i < 4; i++)
#pragma unroll
        for (int j = 0; j < 4; j++) {
            int o2 = ot + i, c = cb + j;
            int tt = o2 >> 4, m = o2 & 15;
            int kt = c >> 5, q = (c >> 3) & 3, jj = c & 7;
            int ln = q * 16 + m;
            wA[(k * 8 + tt * 2 + kt) * 512 + ln * 8 + jj] = (short)f2bf(a[i][j]);
        }
}

// ---------------------------------------------------------------------------
// k_trans: enc [c][p] -> encP [p][c]
// ---------------------------------------------------------------------------
__global__ __launch_bounds__(256) void k_trans(
    const float* __restrict__ enc, float* __restrict__ encP)
{
    __shared__ float s[64 * 65];
    int t = threadIdx.x;
    int base = blockIdx.x * 64;
#pragma unroll
    for (int r = 0; r < 16; r++) {
        int idx = t + r * 256;
        int p = idx & 63, c = idx >> 6;
        s[p * 65 + c] = enc[c * HWSZ + base + p];
    }
    __syncthreads();
#pragma unroll
    for (int r = 0; r < 16; r++) {
        int idx = t + r * 256;
        int c = idx & 63, p = idx >> 6;
        encP[(base + p) * 64 + c] = s[p * 65 + c];
    }
}

// ---------------------------------------------------------------------------
// k_deform: modulated deformable conv v2 (7x7, pad 3) with w_conv1 folded
// into the weights. MFMA bf16 version, 16x1 px tile, 2304 blocks.
//   sampling: 16 threads/pixel (float4 of channels each), bf16 into LDS
//             in B-fragment order [px][c], double-buffered, 1 barrier/tap
//   compute : wave w = otile w; per tap 2x mfma_f32_16x16x32_bf16
// rev output: [px][64 o]
// ---------------------------------------------------------------------------
__global__ __launch_bounds__(256) void k_deform(
    const float* __restrict__ encP, const float* __restrict__ off,
    const float* __restrict__ msk, const short* __restrict__ wA,
    float* __restrict__ rev)
{
    __shared__ __align__(16) short sm[2][16 * SROW];  // bf16 samples [px][c]
    __shared__ __align__(16) float ep[16 * ROWP];     // epilogue [px][o]

    int t = threadIdx.x;
    int lane = t & 63, w = t >> 6;
    int gy  = blockIdx.x / 12;
    int gx0 = (blockIdx.x % 12) * 16;

    // sampling role
    int ps  = t >> 4;            // pixel 0..15
    int cg  = (t & 15) * 4;      // channel group
    int sgx = gx0 + ps;
    int gp  = gy * WW + sgx;

    // mfma role
    int n = lane & 15, q = lane >> 4;

    f32x4 acc = {0.f, 0.f, 0.f, 0.f};

    float dy = off[gp];
    float dx = off[HWSZ + gp];
    float mm = msk[gp];

    for (int k = 0; k < KK; k++) {
        int ky = k / 7, kx = k % 7;
        float y = (float)(gy  - 3 + ky) + dy;
        float x = (float)(sgx - 3 + kx) + dx;
        float y0f = floorf(y), x0f = floorf(x);
        float wy = y - y0f, wx = x - x0f;
        int iy0 = (int)y0f, ix0 = (int)x0f;
        bool vy0 = (iy0 >=  0) & (iy0 < HH);
        bool vy1 = (iy0 >= -1) & (iy0 < HH - 1);
        bool vx0 = (ix0 >=  0) & (ix0 < WW);
        bool vx1 = (ix0 >= -1) & (ix0 < WW - 1);
        const float4 z4 = make_float4(0.f, 0.f, 0.f, 0.f);
        const float* b00 = encP + (iy0 * WW + ix0) * 64 + cg;
        float4 v00 = (vy0 & vx0) ? *(const float4*)(b00)                : z4;
        float4 v01 = (vy0 & vx1) ? *(const float4*)(b00 + 64)           : z4;
        float4 v10 = (vy1 & vx0) ? *(const float4*)(b00 + WW * 64)      : z4;
        float4 v11 = (vy1 & vx1) ? *(const float4*)(b00 + WW * 64 + 64) : z4;

        // prefetch next-tap offsets (3 regs, kills the off->corner serial hop)
        float dyn = 0.f, dxn = 0.f, mmn = 0.f;
        if (k + 1 < KK) {
            dyn = off[(2 * k + 2) * HWSZ + gp];
            dxn = off[(2 * k + 3) * HWSZ + gp];
            mmn = msk[(k + 1) * HWSZ + gp];
        }

        float a00 = (1.f - wy) * (1.f - wx) * mm;
        float a01 = (1.f - wy) * wx * mm;
        float a10 = wy * (1.f - wx) * mm;
        float a11 = wy * wx * mm;
        float f0 = a00 * v00.x + a01 * v01.x + a10 * v10.x + a11 * v11.x;
        float f1 = a00 * v00.y + a01 * v01.y + a10 * v10.y + a11 * v11.y;
        float f2 = a00 * v00.z + a01 * v01.z + a10 * v10.z + a11 * v11.z;
        float f3 = a00 * v00.w + a01 * v01.w + a10 * v10.w + a11 * v11.w;
        unsigned p0 = (unsigned)f2bf(f0) | ((unsigned)f2bf(f1) << 16);
        unsigned p1 = (unsigned)f2bf(f2) | ((unsigned)f2bf(f3) << 16);
        *(uint2*)&sm[k & 1][ps * SROW + cg] = make_uint2(p0, p1);

        __syncthreads();   // samples(k) visible; dbuf makes one barrier safe

        // B frags from LDS: B[c][px], lane holds c = kt*32 + q*8 + j, px = n
        s16x8 b0 = *(const s16x8*)&sm[k & 1][n * SROW +  0 + q * 8];
        s16x8 b1 = *(const s16x8*)&sm[k & 1][n * SROW + 32 + q * 8];
        // A frags from global (L2-hot, coalesced 1KB/wave)
        s16x8 a0 = *(const s16x8*)&wA[(k * 8 + w * 2 + 0) * 512 + lane * 8];
        s16x8 a1 = *(const s16x8*)&wA[(k * 8 + w * 2 + 1) * 512 + lane * 8];
        acc = __builtin_amdgcn_mfma_f32_16x16x32_bf16(a0, b0, acc, 0, 0, 0);
        acc = __builtin_amdgcn_mfma_f32_16x16x32_bf16(a1, b1, acc, 0, 0, 0);

        dy = dyn; dx = dxn; mm = mmn;
    }

    // epilogue: D[row=q*4+r][col=n] -> ep[px][o] -> coalesced float4 store
#pragma unroll
    for (int r = 0; r < 4; r++)
        ep[n * ROWP + w * 16 + q * 4 + r] = acc[r];
    __syncthreads();
    int px = t >> 4, og = (t & 15) * 4;
    *(float4*)&rev[(gy * WW + gx0 + px) * 64 + og] = *(const float4*)&ep[px * ROWP + og];
}

// ---------------------------------------------------------------------------
// k_fft: per 8x8 patch: e0 = w_proj_in @ enc, then per-channel circular conv.
// ---------------------------------------------------------------------------
__global__ __launch_bounds__(256) void k_fft(
    const float* __restrict__ encPg, const float* __restrict__ wpi,
    const float* __restrict__ krT, float* __restrict__ e1)
{
    __shared__ __align__(16) float encP[64 * ROWP];
    __shared__ __align__(16) float e0[64 * ROWP];
    int t = threadIdx.x;
    int pbx = blockIdx.x % 24, pby = blockIdx.x / 24;
    int gx0 = pbx * 8, gy0 = pby * 8;

#pragma unroll
    for (int r = 0; r < 4; r++) {
        int idx = t + r * 256;
        int px = idx >> 4, cgp = (idx & 15) * 4;
        int gy = gy0 + (px >> 3), gx = gx0 + (px & 7);
        *(float4*)&encP[px * ROWP + cgp] =
            *(const float4*)&encPg[(gy * WW + gx) * 64 + cgp];
    }
    __syncthreads();

    int ot = (t >> 4) * 4, pxl = t & 15;
    float acc[4][4];
#pragma unroll
    for (int i = 0; i < 4; i++)
#pragma unroll
        for (int j = 0; j < 4; j++) acc[i][j] = 0.f;
#pragma unroll
    for (int c4 = 0; c4 < 16; c4++) {
        float4 wv4[4], sv[4];
#pragma unroll
        for (int i = 0; i < 4; i++)
            wv4[i] = *(const float4*)&wpi[(ot + i) * 64 + c4 * 4];
#pragma unroll
        for (int j = 0; j < 4; j++)
            sv[j] = *(const float4*)&encP[(pxl + 16 * j) * ROWP + c4 * 4];
#pragma unroll
        for (int i = 0; i < 4; i++)
#pragma unroll
            for (int j = 0; j < 4; j++)
                acc[i][j] += wv4[i].x * sv[j].x + wv4[i].y * sv[j].y
                           + wv4[i].z * sv[j].z + wv4[i].w * sv[j].w;
    }
#pragma unroll
    for (int j = 0; j < 4; j++) {
        float4 dv = make_float4(acc[0][j], acc[1][j], acc[2][j], acc[3][j]);
        *(float4*)&e0[(pxl + 16 * j) * ROWP + ot] = dv;
    }
    __syncthreads();

    int o = t & 63;
    int yb = t >> 6;
#pragma unroll
    for (int yy = 0; yy < 2; yy++) {
        int y = yb + yy * 4;
        float outr[8];
#pragma unroll
        for (int x = 0; x < 8; x++) outr[x] = 0.f;
#pragma unroll
        for (int u = 0; u < 8; u++) {
            int ry = (y - u + 8) & 7;
            float row[8];
#pragma unroll
            for (int rx = 0; rx < 8; rx++)
                row[rx] = e0[(ry * 8 + rx) * ROWP + o];
#pragma unroll
            for (int v = 0; v < 8; v++) {
                float kv = krT[(u * 8 + v) * 64 + o];
#pragma unroll
                for (int x = 0; x < 8; x++)
                    outr[x] += kv * row[(x - v + 8) & 7];
            }
        }
        int gy = gy0 + y;
#pragma unroll
        for (int x = 0; x < 8; x++)
            e1[(gy * WW + gx0 + x) * 64 + o] = outr[x];
    }
}

// ---------------------------------------------------------------------------
// k_conv3: e3 = conv3x3(e1 + rev, w_conv2, pad 1)
// ---------------------------------------------------------------------------
__global__ __launch_bounds__(256) void k_conv3(
    const float* __restrict__ e1, const float* __restrict__ rev,
    const float* __restrict__ w2T, float* __restrict__ e3)
{
    __shared__ __align__(16) float tl[108 * ROWP];
    int t = threadIdx.x;
    int bx = blockIdx.x % 12, by = blockIdx.x / 12;
    int gx0 = bx * 16, gy0 = by * 4;

#pragma unroll
    for (int r = 0; r < 27; r++) {
        int idx = t + r * 256;
        int c = idx & 63, hp = idx >> 6;
        int hy = hp / 18, hx = hp % 18;
        int gy = gy0 + hy - 1, gx = gx0 + hx - 1;
        float v = 0.f;
        if (gy >= 0 && gy < HH && gx >= 0 && gx < WW) {
            int gpp = gy * WW + gx;
            v = e1[gpp * 64 + c] + rev[gpp * 64 + c];
        }
        tl[hp * ROWP + c] = v;
    }
    __syncthreads();

    int ot = (t >> 4) * 4, pxl = t & 15;
    float acc[4][4];
#pragma unroll
    for (int i = 0; i < 4; i++)
#pragma unroll
        for (int j = 0; j < 4; j++) acc[i][j] = 0.f;

    for (int tap = 0; tap < 9; tap++) {
        int dy = tap / 3, dx = tap % 3;
        const float* wt = w2T + tap * 4096;
#pragma unroll
        for (int c4 = 0; c4 < 16; c4++) {
            float4 wv4[4], sv[4];
#pragma unroll
            for (int i = 0; i < 4; i++)
                wv4[i] = *(const float4*)&wt[(ot + i) * 64 + c4 * 4];
#pragma unroll
            for (int j = 0; j < 4; j++) {
                int hp = (j + dy) * 18 + (pxl + dx);
                sv[j] = *(const float4*)&tl[hp * ROWP + c4 * 4];
            }
#pragma unroll
            for (int i = 0; i < 4; i++)
#pragma unroll
                for (int j = 0; j < 4; j++)
                    acc[i][j] += wv4[i].x * sv[j].x + wv4[i].y * sv[j].y
                               + wv4[i].z * sv[j].z + wv4[i].w * sv[j].w;
        }
    }
#pragma unroll
    for (int j = 0; j < 4; j++) {
        int gpp = (gy0 + j) * WW + gx0 + pxl;
        float4 rv = make_float4(acc[0][j], acc[1][j], acc[2][j], acc[3][j]);
        *(float4*)&e3[gpp * 64 + ot] = rv;
    }
}

// ---------------------------------------------------------------------------
// k_out: feat = [e3 ; dec], g = w_proj_out @ feat, out = g[:64] * g[64:]
// ---------------------------------------------------------------------------
#define ROWF 132

__global__ __launch_bounds__(256) void k_out(
    const float* __restrict__ e3, const float* __restrict__ dec,
    const float* __restrict__ wpo, float* __restrict__ out)
{
    __shared__ __align__(16) float f[64 * ROWF];
    int t = threadIdx.x;
    int bx = blockIdx.x % 12, by = blockIdx.x / 12;
    int gx0 = bx * 16, gy0 = by * 4;

#pragma unroll
    for (int r = 0; r < 16; r++) {
        int idx = t + r * 256;
        int c = idx & 63, px = idx >> 6;
        int gpp = (gy0 + (px >> 4)) * WW + gx0 + (px & 15);
        f[px * ROWF + c] = e3[gpp * 64 + c];
    }
#pragma unroll
    for (int r = 0; r < 16; r++) {
        int idx = t + r * 256;
        int px = idx & 63, c = idx >> 6;
        int gpp = (gy0 + (px >> 4)) * WW + gx0 + (px & 15);
        f[px * ROWF + 64 + c] = dec[c * HWSZ + gpp];
    }
    __syncthreads();

    int ot = (t >> 4) * 4, pxl = t & 15;
    float a1[4][4], a2[4][4];
#pragma unroll
    for (int i = 0; i < 4; i++)
#pragma unroll
        for (int j = 0; j < 4; j++) { a1[i][j] = 0.f; a2[i][j] = 0.f; }

#pragma unroll
    for (int c4 = 0; c4 < 32; c4++) {
        float4 w1[4], w2[4], sv[4];
#pragma unroll
        for (int i = 0; i < 4; i++) {
            w1[i] = *(const float4*)&wpo[(ot + i) * 128 + c4 * 4];
            w2[i] = *(const float4*)&wpo[(ot + i + 64) * 128 + c4 * 4];
        }
#pragma unroll
        for (int j = 0; j < 4; j++)
            sv[j] = *(const float4*)&f[(pxl + 16 * j) * ROWF + c4 * 4];
#pragma unroll
        for (int i = 0; i < 4; i++)
#pragma unroll
            for (int j = 0; j < 4; j++) {
                a1[i][j] += w1[i].x * sv[j].x + w1[i].y * sv[j].y
                          + w1[i].z * sv[j].z + w1[i].w * sv[j].w;
                a2[i][j] += w2[i].x * sv[j].x + w2[i].y * sv[j].y
                          + w2[i].z * sv[j].z + w2[i].w * sv[j].w;
            }
    }
#pragma unroll
    for (int j = 0; j < 4; j++) {
        int gpp = (gy0 + j) * WW + gx0 + pxl;
#pragma unroll
        for (int i = 0; i < 4; i++)
            out[(ot + i) * HWSZ + gpp] = a1[i][j] * a2[i][j];
    }
}

// ---------------------------------------------------------------------------
extern "C" void kernel_launch(void* const* d_in, const int* in_sizes, int n_in,
                              void* d_out, int out_size, void* d_ws, size_t ws_size,
                              hipStream_t stream)
{
    const float* enc  = (const float*)d_in[0];
    const float* dec  = (const float*)d_in[1];
    const float* ioff = (const float*)d_in[2];
    const float* iwt  = (const float*)d_in[3];
    const float* wpi  = (const float*)d_in[4];
    const float* fw   = (const float*)d_in[5];
    const float* wpo  = (const float*)d_in[6];
    const float* wd   = (const float*)d_in[7];
    const float* wc1  = (const float*)d_in[8];
    const float* wc2  = (const float*)d_in[9];
    float* out = (float*)d_out;
    float* ws  = (float*)d_ws;

    float* krT  = ws;                 //    4096
    float* w2T  = ws + 4096;          //   36864
    float* rev  = ws + 40960;         // 2359296  [px][64]
    float* e1   = ws + 2400256;       // 2359296  [px][64]
    float* e3   = ws + 4759552;       // 2359296  [px][64]
    float* encP = ws + 7118848;       // 2359296  [px][64]
    short* wA   = (short*)(ws + 9478144);  // 200704 bf16 (100352 floats)
    // total ~38.3 MB

    hipLaunchKernelGGL(k_prep,   dim3(49),   dim3(256), 0, stream, fw, wd, wc2, wc1, krT, w2T, wA);
    hipLaunchKernelGGL(k_trans,  dim3(576),  dim3(256), 0, stream, enc, encP);
    hipLaunchKernelGGL(k_deform, dim3(2304), dim3(256), 0, stream, encP, ioff, iwt, wA, rev);
    hipLaunchKernelGGL(k_fft,    dim3(576),  dim3(256), 0, stream, encP, wpi, krT, e1);
    hipLaunchKernelGGL(k_conv3,  dim3(576),  dim3(256), 0, stream, e1, rev, w2T, e3);
    hipLaunchKernelGGL(k_out,    dim3(576),  dim3(256), 0, stream, e3, dec, wpo, out);
}

// Round 5
// 460.940 us; speedup vs baseline: 23.4001x; 1.5348x over previous
//
#include <hip/hip_runtime.h>
#include <math.h>

#define CH    64
#define WW    192
#define HH    192
#define HWSZ  (192*192)
#define KK    49
#define ROWP  68   // padded LDS row (fp32 kernels)
#define SROW  72   // bf16 sample row stride in shorts (144B, 16B-multiple)

typedef __attribute__((ext_vector_type(8))) short s16x8;   // 8 bf16 = 4 VGPR
typedef __attribute__((ext_vector_type(4))) float f32x4;

__device__ __forceinline__ unsigned short f2bf(float f) {
    union { float f; unsigned u; } v; v.f = f;
    unsigned u = v.u + 0x7FFFu + ((v.u >> 16) & 1u);   // RNE
    return (unsigned short)(u >> 16);
}

// pack two floats to bf16x2 (round-half-up): 2 adds + 1 v_perm
__device__ __forceinline__ unsigned pkbf(float lo, float hi) {
    return __builtin_amdgcn_perm(__float_as_uint(hi) + 0x8000u,
                                 __float_as_uint(lo) + 0x8000u, 0x07060302u);
}

// ---------------------------------------------------------------------------
// k_prep (grid 49 x 256):
//  - krT: circular-conv kernels from fft_w (grid-stride)
//  - w2T: tap-major 3x3 weights (grid-stride)
//  - fold: wfold[k][o2][c] = sum_o wc1[o2][o] * wd[o][c][k]  (block per k)
//    packed bf16 in MFMA A-fragment lane order.
// ---------------------------------------------------------------------------
__device__ const float c_cos8[8] = {
    1.f, 0.70710678118654752f, 0.f, -0.70710678118654752f,
   -1.f, -0.70710678118654752f, 0.f, 0.70710678118654752f };

__global__ __launch_bounds__(256) void k_prep(
    const float* __restrict__ fw,   // [64,1,1,8,5]
    const float* __restrict__ wd,   // [64,64,7,7]
    const float* __restrict__ w2,   // [64,64,3,3]
    const float* __restrict__ wc1,  // [64,64,1,1]
    float* __restrict__ krT,        // [64 uv][64 c]
    float* __restrict__ w2T,        // [9][64 o][64 c]
    short* __restrict__ wA)         // packed bf16 A-fragments [49*8*512]
{
    int tid = blockIdx.x * blockDim.x + threadIdx.x;
    int nt  = gridDim.x * blockDim.x;
    for (int t = tid; t < 64 * 64; t += nt) {
        int uv = t >> 6, c = t & 63;
        int u = uv >> 3, v = uv & 7;
        float acc = 0.f;
        for (int ky = 0; ky < 8; ky++)
            for (int kx = 0; kx < 8; kx++) {
                float wv = (kx <= 4) ? fw[c * 40 + ky * 5 + kx]
                                     : fw[c * 40 + ((8 - ky) & 7) * 5 + (8 - kx)];
                acc += wv * c_cos8[(ky * u + kx * v) & 7];
            }
        krT[uv * 64 + c] = acc * (1.f / 64.f);
    }
    for (int t = tid; t < 9 * 4096; t += nt) {
        int tap = t / 4096, rem = t & 4095;
        int o = rem >> 6, c = rem & 63;
        w2T[t] = w2[(o * 64 + c) * 9 + tap];
    }

    // ---- fold + pack: one block per tap k ----
    __shared__ float wdk [64 * ROWP];
    __shared__ float wc1s[64 * ROWP];
    int k = blockIdx.x;
    int t = threadIdx.x;
#pragma unroll
    for (int r = 0; r < 16; r++) {
        int idx = t + r * 256;
        int o = idx >> 6, c = idx & 63;
        wdk [o * ROWP + c] = wd[(o * 64 + c) * KK + k];
        wc1s[o * ROWP + c] = wc1[o * 64 + c];
    }
    __syncthreads();

    int ot = (t >> 4) * 4, cb = (t & 15) * 4;
    float a[4][4];
#pragma unroll
    for (int i = 0; i < 4; i++)
#pragma unroll
        for (int j = 0; j < 4; j++) a[i][j] = 0.f;
    for (int o = 0; o < 64; o++) {
        float wv_[4], sv_[4];
#pragma unroll
        for (int i = 0; i < 4; i++) wv_[i] = wc1s[(ot + i) * ROWP + o];
#pragma unroll
        for (int j = 0; j < 4; j++) sv_[j] = wdk[o * ROWP + cb + j];
#pragma unroll
        for (int i = 0; i < 4; i++)
#pragma unroll
            for (int j = 0; j < 4; j++) a[i][j] += wv_[i] * sv_[j];
    }
#pragma unroll
    for (int i = 0; i < 4; i++)
#pragma unroll
        for (int j = 0; j < 4; j++) {
            int o2 = ot + i, c = cb + j;
            int tt = o2 >> 4, m = o2 & 15;
            int kt = c >> 5, q = (c >> 3) & 3, jj = c & 7;
            int ln = q * 16 + m;
            wA[(k * 8 + tt * 2 + kt) * 512 + ln * 8 + jj] = (short)f2bf(a[i][j]);
        }
}

// ---------------------------------------------------------------------------
// k_trans: enc [c][p] -> encP [p][c]
// ---------------------------------------------------------------------------
__global__ __launch_bounds__(256) void k_trans(
    const float* __restrict__ enc, float* __restrict__ encP)
{
    __shared__ float s[64 * 65];
    int t = threadIdx.x;
    int base = blockIdx.x * 64;
#pragma unroll
    for (int r = 0; r < 16; r++) {
        int idx = t + r * 256;
        int p = idx & 63, c = idx >> 6;
        s[p * 65 + c] = enc[c * HWSZ + base + p];
    }
    __syncthreads();
#pragma unroll
    for (int r = 0; r < 16; r++) {
        int idx = t + r * 256;
        int c = idx & 63, p = idx >> 6;
        encP[(base + p) * 64 + c] = s[p * 65 + c];
    }
}

// ---------------------------------------------------------------------------
// k_deform: barrier-free MFMA deformable conv (7x7, pad 3), w_conv1 folded.
// Wave = 16x1 px strip, all 64 outputs. Per tap per wave:
//   sampling lane (p=lane>>2, g=lane&3): 16 ch of pixel p, 4x float4/corner
//     (4-lane group = contiguous 256B), validity folded into blend weights,
//     clamped addresses (no cndmask on data)
//   wave-private LDS bounce (no __syncthreads): 2x ds_write_b128 ->
//     2x ds_read_b128 in B-frag order; 8 MFMAs (4 o-tiles x 2 kt)
// XCD swizzle: blockIdx&7 -> 24-row band (1.5MB working set, L2-resident).
// ---------------------------------------------------------------------------
__global__ __launch_bounds__(256) void k_deform(
    const float* __restrict__ encP, const float* __restrict__ off,
    const float* __restrict__ msk, const short* __restrict__ wA,
    float* __restrict__ rev)
{
    __shared__ __align__(16) short sm[4][16 * SROW];  // per-wave private

    int t = threadIdx.x;
    int lane = t & 63, w = t >> 6;
    int b = blockIdx.x;
    int xcd = b & 7, blk = b >> 3;
    int gy  = xcd * 24 + blk / 3;
    int gx0 = (blk % 3) * 64 + w * 16;

    // sampling role
    int sp = lane >> 2, g = lane & 3;
    int sgx  = gx0 + sp;
    int gp_s = gy * WW + sgx;

    // mfma role
    int n = lane & 15, q = lane >> 4;
    int gp_m = gy * WW + gx0 + n;

    short* smw = &sm[w][0];

    f32x4 acc[4];
#pragma unroll
    for (int ot = 0; ot < 4; ot++) acc[ot] = (f32x4){0.f, 0.f, 0.f, 0.f};

    float dy = off[gp_s];
    float dx = off[HWSZ + gp_s];
    float mm = msk[gp_s];

    for (int k = 0; k < KK; k++) {
        int ky = k / 7, kx = k % 7;
        float y = (float)(gy  - 3 + ky) + dy;
        float x = (float)(sgx - 3 + kx) + dx;
        float y0f = floorf(y), x0f = floorf(x);
        float wy = y - y0f, wx = x - x0f;
        int iy0 = (int)y0f, ix0 = (int)x0f;
        int iy1 = iy0 + 1, ix1 = ix0 + 1;
        bool vy0 = (iy0 >= 0) & (iy0 < HH);
        bool vy1 = (iy1 >= 0) & (iy1 < HH);
        bool vx0 = (ix0 >= 0) & (ix0 < WW);
        bool vx1 = (ix1 >= 0) & (ix1 < WW);
        int iy0c = min(max(iy0, 0), HH - 1), iy1c = min(max(iy1, 0), HH - 1);
        int ix0c = min(max(ix0, 0), WW - 1), ix1c = min(max(ix1, 0), WW - 1);
        float a00 = (vy0 & vx0) ? (1.f - wy) * (1.f - wx) * mm : 0.f;
        float a01 = (vy0 & vx1) ? (1.f - wy) * wx * mm : 0.f;
        float a10 = (vy1 & vx0) ? wy * (1.f - wx) * mm : 0.f;
        float a11 = (vy1 & vx1) ? wy * wx * mm : 0.f;

        const float4* p00 = (const float4*)(encP + (iy0c * WW + ix0c) * 64 + g * 16);
        const float4* p01 = (const float4*)(encP + (iy0c * WW + ix1c) * 64 + g * 16);
        const float4* p10 = (const float4*)(encP + (iy1c * WW + ix0c) * 64 + g * 16);
        const float4* p11 = (const float4*)(encP + (iy1c * WW + ix1c) * 64 + g * 16);
        float4 c00[4], c01[4], c10[4], c11[4];
#pragma unroll
        for (int i = 0; i < 4; i++) {
            c00[i] = p00[i]; c01[i] = p01[i];
            c10[i] = p10[i]; c11[i] = p11[i];
        }

        // prefetch next-tap offsets (breaks the off->corner serial hop)
        float dyn = 0.f, dxn = 0.f, mmn = 0.f;
        if (k + 1 < KK) {
            dyn = off[(2 * k + 2) * HWSZ + gp_s];
            dxn = off[(2 * k + 3) * HWSZ + gp_s];
            mmn = msk[(k + 1) * HWSZ + gp_s];
        }

        // A-frag loads (static addresses, L2-hot, independent of samples)
        s16x8 af[4][2];
#pragma unroll
        for (int ot = 0; ot < 4; ot++)
#pragma unroll
            for (int kt = 0; kt < 2; kt++)
                af[ot][kt] = *(const s16x8*)&wA[(k * 8 + ot * 2 + kt) * 512 + lane * 8];

        // blend + pack bf16 + wave-private LDS write (no barrier)
        unsigned pk[8];
#pragma unroll
        for (int i = 0; i < 4; i++) {
            float f0 = a00 * c00[i].x + a01 * c01[i].x + a10 * c10[i].x + a11 * c11[i].x;
            float f1 = a00 * c00[i].y + a01 * c01[i].y + a10 * c10[i].y + a11 * c11[i].y;
            float f2 = a00 * c00[i].z + a01 * c01[i].z + a10 * c10[i].z + a11 * c11[i].z;
            float f3 = a00 * c00[i].w + a01 * c01[i].w + a10 * c10[i].w + a11 * c11[i].w;
            pk[2 * i]     = pkbf(f0, f1);
            pk[2 * i + 1] = pkbf(f2, f3);
        }
        *(uint4*)&smw[sp * SROW + g * 16]     = make_uint4(pk[0], pk[1], pk[2], pk[3]);
        *(uint4*)&smw[sp * SROW + g * 16 + 8] = make_uint4(pk[4], pk[5], pk[6], pk[7]);

        // B-frags: same-wave LDS read (compiler inserts lgkmcnt wait only)
        s16x8 b0 = *(const s16x8*)&smw[n * SROW +  0 + q * 8];
        s16x8 b1 = *(const s16x8*)&smw[n * SROW + 32 + q * 8];

#pragma unroll
        for (int ot = 0; ot < 4; ot++) {
            acc[ot] = __builtin_amdgcn_mfma_f32_16x16x32_bf16(af[ot][0], b0, acc[ot], 0, 0, 0);
            acc[ot] = __builtin_amdgcn_mfma_f32_16x16x32_bf16(af[ot][1], b1, acc[ot], 0, 0, 0);
        }

        dy = dyn; dx = dxn; mm = mmn;
    }

    // epilogue: lane (q,n) holds o = ot*16 + q*4 + r for pixel n
#pragma unroll
    for (int ot = 0; ot < 4; ot++) {
        float4 rv = make_float4(acc[ot][0], acc[ot][1], acc[ot][2], acc[ot][3]);
        *(float4*)&rev[gp_m * 64 + ot * 16 + q * 4] = rv;
    }
}

// ---------------------------------------------------------------------------
// k_fft: per 8x8 patch: e0 = w_proj_in @ enc, then per-channel circular conv.
// ---------------------------------------------------------------------------
__global__ __launch_bounds__(256) void k_fft(
    const float* __restrict__ encPg, const float* __restrict__ wpi,
    const float* __restrict__ krT, float* __restrict__ e1)
{
    __shared__ __align__(16) float encP[64 * ROWP];
    __shared__ __align__(16) float e0[64 * ROWP];
    int t = threadIdx.x;
    int pbx = blockIdx.x % 24, pby = blockIdx.x / 24;
    int gx0 = pbx * 8, gy0 = pby * 8;

#pragma unroll
    for (int r = 0; r < 4; r++) {
        int idx = t + r * 256;
        int px = idx >> 4, cgp = (idx & 15) * 4;
        int gy = gy0 + (px >> 3), gx = gx0 + (px & 7);
        *(float4*)&encP[px * ROWP + cgp] =
            *(const float4*)&encPg[(gy * WW + gx) * 64 + cgp];
    }
    __syncthreads();

    int ot = (t >> 4) * 4, pxl = t & 15;
    float acc[4][4];
#pragma unroll
    for (int i = 0; i < 4; i++)
#pragma unroll
        for (int j = 0; j < 4; j++) acc[i][j] = 0.f;
#pragma unroll
    for (int c4 = 0; c4 < 16; c4++) {
        float4 wv4[4], sv[4];
#pragma unroll
        for (int i = 0; i < 4; i++)
            wv4[i] = *(const float4*)&wpi[(ot + i) * 64 + c4 * 4];
#pragma unroll
        for (int j = 0; j < 4; j++)
            sv[j] = *(const float4*)&encP[(pxl + 16 * j) * ROWP + c4 * 4];
#pragma unroll
        for (int i = 0; i < 4; i++)
#pragma unroll
            for (int j = 0; j < 4; j++)
                acc[i][j] += wv4[i].x * sv[j].x + wv4[i].y * sv[j].y
                           + wv4[i].z * sv[j].z + wv4[i].w * sv[j].w;
    }
#pragma unroll
    for (int j = 0; j < 4; j++) {
        float4 dv = make_float4(acc[0][j], acc[1][j], acc[2][j], acc[3][j]);
        *(float4*)&e0[(pxl + 16 * j) * ROWP + ot] = dv;
    }
    __syncthreads();

    int o = t & 63;
    int yb = t >> 6;
#pragma unroll
    for (int yy = 0; yy < 2; yy++) {
        int y = yb + yy * 4;
        float outr[8];
#pragma unroll
        for (int x = 0; x < 8; x++) outr[x] = 0.f;
#pragma unroll
        for (int u = 0; u < 8; u++) {
            int ry = (y - u + 8) & 7;
            float row[8];
#pragma unroll
            for (int rx = 0; rx < 8; rx++)
                row[rx] = e0[(ry * 8 + rx) * ROWP + o];
#pragma unroll
            for (int v = 0; v < 8; v++) {
                float kv = krT[(u * 8 + v) * 64 + o];
#pragma unroll
                for (int x = 0; x < 8; x++)
                    outr[x] += kv * row[(x - v + 8) & 7];
            }
        }
        int gy = gy0 + y;
#pragma unroll
        for (int x = 0; x < 8; x++)
            e1[(gy * WW + gx0 + x) * 64 + o] = outr[x];
    }
}

// ---------------------------------------------------------------------------
// k_conv3: e3 = conv3x3(e1 + rev, w_conv2, pad 1)
// ---------------------------------------------------------------------------
__global__ __launch_bounds__(256) void k_conv3(
    const float* __restrict__ e1, const float* __restrict__ rev,
    const float* __restrict__ w2T, float* __restrict__ e3)
{
    __shared__ __align__(16) float tl[108 * ROWP];
    int t = threadIdx.x;
    int bx = blockIdx.x % 12, by = blockIdx.x / 12;
    int gx0 = bx * 16, gy0 = by * 4;

#pragma unroll
    for (int r = 0; r < 27; r++) {
        int idx = t + r * 256;
        int c = idx & 63, hp = idx >> 6;
        int hy = hp / 18, hx = hp % 18;
        int gy = gy0 + hy - 1, gx = gx0 + hx - 1;
        float v = 0.f;
        if (gy >= 0 && gy < HH && gx >= 0 && gx < WW) {
            int gpp = gy * WW + gx;
            v = e1[gpp * 64 + c] + rev[gpp * 64 + c];
        }
        tl[hp * ROWP + c] = v;
    }
    __syncthreads();

    int ot = (t >> 4) * 4, pxl = t & 15;
    float acc[4][4];
#pragma unroll
    for (int i = 0; i < 4; i++)
#pragma unroll
        for (int j = 0; j < 4; j++) acc[i][j] = 0.f;

    for (int tap = 0; tap < 9; tap++) {
        int dy = tap / 3, dx = tap % 3;
        const float* wt = w2T + tap * 4096;
#pragma unroll
        for (int c4 = 0; c4 < 16; c4++) {
            float4 wv4[4], sv[4];
#pragma unroll
            for (int i = 0; i < 4; i++)
                wv4[i] = *(const float4*)&wt[(ot + i) * 64 + c4 * 4];
#pragma unroll
            for (int j = 0; j < 4; j++) {
                int hp = (j + dy) * 18 + (pxl + dx);
                sv[j] = *(const float4*)&tl[hp * ROWP + c4 * 4];
            }
#pragma unroll
            for (int i = 0; i < 4; i++)
#pragma unroll
                for (int j = 0; j < 4; j++)
                    acc[i][j] += wv4[i].x * sv[j].x + wv4[i].y * sv[j].y
                               + wv4[i].z * sv[j].z + wv4[i].w * sv[j].w;
        }
    }
#pragma unroll
    for (int j = 0; j < 4; j++) {
        int gpp = (gy0 + j) * WW + gx0 + pxl;
        float4 rv = make_float4(acc[0][j], acc[1][j], acc[2][j], acc[3][j]);
        *(float4*)&e3[gpp * 64 + ot] = rv;
    }
}

// ---------------------------------------------------------------------------
// k_out: feat = [e3 ; dec], g = w_proj_out @ feat, out = g[:64] * g[64:]
// ---------------------------------------------------------------------------
#define ROWF 132

__global__ __launch_bounds__(256) void k_out(
    const float* __restrict__ e3, const float* __restrict__ dec,
    const float* __restrict__ wpo, float* __restrict__ out)
{
    __shared__ __align__(16) float f[64 * ROWF];
    int t = threadIdx.x;
    int bx = blockIdx.x % 12, by = blockIdx.x / 12;
    int gx0 = bx * 16, gy0 = by * 4;

#pragma unroll
    for (int r = 0; r < 16; r++) {
        int idx = t + r * 256;
        int c = idx & 63, px = idx >> 6;
        int gpp = (gy0 + (px >> 4)) * WW + gx0 + (px & 15);
        f[px * ROWF + c] = e3[gpp * 64 + c];
    }
#pragma unroll
    for (int r = 0; r < 16; r++) {
        int idx = t + r * 256;
        int px = idx & 63, c = idx >> 6;
        int gpp = (gy0 + (px >> 4)) * WW + gx0 + (px & 15);
        f[px * ROWF + 64 + c] = dec[c * HWSZ + gpp];
    }
    __syncthreads();

    int ot = (t >> 4) * 4, pxl = t & 15;
    float a1[4][4], a2[4][4];
#pragma unroll
    for (int i = 0; i < 4; i++)
#pragma unroll
        for (int j = 0; j < 4; j++) { a1[i][j] = 0.f; a2[i][j] = 0.f; }

#pragma unroll
    for (int c4 = 0; c4 < 32; c4++) {
        float4 w1[4], w2[4], sv[4];
#pragma unroll
        for (int i = 0; i < 4; i++) {
            w1[i] = *(const float4*)&wpo[(ot + i) * 128 + c4 * 4];
            w2[i] = *(const float4*)&wpo[(ot + i + 64) * 128 + c4 * 4];
        }
#pragma unroll
        for (int j = 0; j < 4; j++)
            sv[j] = *(const float4*)&f[(pxl + 16 * j) * ROWF + c4 * 4];
#pragma unroll
        for (int i = 0; i < 4; i++)
#pragma unroll
            for (int j = 0; j < 4; j++) {
                a1[i][j] += w1[i].x * sv[j].x + w1[i].y * sv[j].y
                          + w1[i].z * sv[j].z + w1[i].w * sv[j].w;
                a2[i][j] += w2[i].x * sv[j].x + w2[i].y * sv[j].y
                          + w2[i].z * sv[j].z + w2[i].w * sv[j].w;
            }
    }
#pragma unroll
    for (int j = 0; j < 4; j++) {
        int gpp = (gy0 + j) * WW + gx0 + pxl;
#pragma unroll
        for (int i = 0; i < 4; i++)
            out[(ot + i) * HWSZ + gpp] = a1[i][j] * a2[i][j];
    }
}

// ---------------------------------------------------------------------------
extern "C" void kernel_launch(void* const* d_in, const int* in_sizes, int n_in,
                              void* d_out, int out_size, void* d_ws, size_t ws_size,
                              hipStream_t stream)
{
    const float* enc  = (const float*)d_in[0];
    const float* dec  = (const float*)d_in[1];
    const float* ioff = (const float*)d_in[2];
    const float* iwt  = (const float*)d_in[3];
    const float* wpi  = (const float*)d_in[4];
    const float* fw   = (const float*)d_in[5];
    const float* wpo  = (const float*)d_in[6];
    const float* wd   = (const float*)d_in[7];
    const float* wc1  = (const float*)d_in[8];
    const float* wc2  = (const float*)d_in[9];
    float* out = (float*)d_out;
    float* ws  = (float*)d_ws;

    float* krT  = ws;                 //    4096
    float* w2T  = ws + 4096;          //   36864
    float* rev  = ws + 40960;         // 2359296  [px][64]
    float* e1   = ws + 2400256;       // 2359296  [px][64]
    float* e3   = ws + 4759552;       // 2359296  [px][64]
    float* encP = ws + 7118848;       // 2359296  [px][64]
    short* wA   = (short*)(ws + 9478144);  // 200704 bf16

    hipLaunchKernelGGL(k_prep,   dim3(49),  dim3(256), 0, stream, fw, wd, wc2, wc1, krT, w2T, wA);
    hipLaunchKernelGGL(k_trans,  dim3(576), dim3(256), 0, stream, enc, encP);
    hipLaunchKernelGGL(k_deform, dim3(576), dim3(256), 0, stream, encP, ioff, iwt, wA, rev);
    hipLaunchKernelGGL(k_fft,    dim3(576), dim3(256), 0, stream, encP, wpi, krT, e1);
    hipLaunchKernelGGL(k_conv3,  dim3(576), dim3(256), 0, stream, e1, rev, w2T, e3);
    hipLaunchKernelGGL(k_out,    dim3(576), dim3(256), 0, stream, e3, dec, wpo, out);
}

// Round 6
// 343.007 us; speedup vs baseline: 31.4456x; 1.3438x over previous
//
#include <hip/hip_runtime.h>
#include <math.h>

#define CH    64
#define WW    192
#define HH    192
#define HWSZ  (192*192)
#define KK    49
#define ROWP  68   // padded fp32 LDS row (dwords)
#define SROW  72   // bf16 row stride in shorts (144B)
#define C3ROW 72   // conv3 staged px stride (shorts)
#define OROW  136  // k_out staged px stride (shorts, 128ch + 8 pad)

typedef __attribute__((ext_vector_type(8))) short s16x8;   // 8 bf16 = 4 VGPR
typedef __attribute__((ext_vector_type(4))) float f32x4;

__device__ __forceinline__ unsigned short f2bf(float f) {
    union { float f; unsigned u; } v; v.f = f;
    unsigned u = v.u + 0x7FFFu + ((v.u >> 16) & 1u);   // RNE
    return (unsigned short)(u >> 16);
}

// pack two floats to bf16x2 (round-half-up): 2 adds + 1 v_perm
__device__ __forceinline__ unsigned pkbf(float lo, float hi) {
    return __builtin_amdgcn_perm(__float_as_uint(hi) + 0x8000u,
                                 __float_as_uint(lo) + 0x8000u, 0x07060302u);
}

// ---------------------------------------------------------------------------
// k_prep (grid 49 x 256):
//  - krT: circular-conv kernels from fft_w
//  - A-fragment packs (bf16, verified lane order from R4 wA):
//      wA  : wc1-folded deform weights  [49 taps][4 ot][2 kt]
//      w2A : conv3x3 weights            [9 taps][4 ot][2 kt]
//      wpoA: proj_out 128x128           [8 ot][4 kt]
//      wpiA: proj_in  64x64             [4 ot][2 kt]
// ---------------------------------------------------------------------------
__device__ const float c_cos8[8] = {
    1.f, 0.70710678118654752f, 0.f, -0.70710678118654752f,
   -1.f, -0.70710678118654752f, 0.f, 0.70710678118654752f };

__global__ __launch_bounds__(256) void k_prep(
    const float* __restrict__ fw,   // [64,1,1,8,5]
    const float* __restrict__ wd,   // [64,64,7,7]
    const float* __restrict__ w2,   // [64,64,3,3]
    const float* __restrict__ wc1,  // [64,64,1,1]
    const float* __restrict__ wpo,  // [128,128]
    const float* __restrict__ wpi,  // [64,64]
    float* __restrict__ krT,        // [64 uv][64 c]
    short* __restrict__ wA,         // [49*8*512]
    short* __restrict__ w2A,        // [9*8*512]
    short* __restrict__ wpoA,       // [32*512]
    short* __restrict__ wpiA)       // [8*512]
{
    int tid = blockIdx.x * blockDim.x + threadIdx.x;
    int nt  = gridDim.x * blockDim.x;
    for (int t = tid; t < 64 * 64; t += nt) {
        int uv = t >> 6, c = t & 63;
        int u = uv >> 3, v = uv & 7;
        float acc = 0.f;
        for (int ky = 0; ky < 8; ky++)
            for (int kx = 0; kx < 8; kx++) {
                float wv = (kx <= 4) ? fw[c * 40 + ky * 5 + kx]
                                     : fw[c * 40 + ((8 - ky) & 7) * 5 + (8 - kx)];
                acc += wv * c_cos8[(ky * u + kx * v) & 7];
            }
        krT[uv * 64 + c] = acc * (1.f / 64.f);
    }
    // conv3 weights -> A-frags (tap-major)
    for (int t = tid; t < 9 * 4096; t += nt) {
        int tap = t / 4096, rem = t & 4095;
        int o = rem >> 6, c = rem & 63;
        float v = w2[(o * 64 + c) * 9 + tap];
        int fi = tap * 8 + (o >> 4) * 2 + (c >> 5);
        int ln = ((c >> 3) & 3) * 16 + (o & 15);
        w2A[fi * 512 + ln * 8 + (c & 7)] = (short)f2bf(v);
    }
    // proj_out 128x128 -> A-frags
    for (int t = tid; t < 128 * 128; t += nt) {
        int o = t >> 7, c = t & 127;
        int fi = (o >> 4) * 4 + (c >> 5);
        int ln = ((c >> 3) & 3) * 16 + (o & 15);
        wpoA[fi * 512 + ln * 8 + (c & 7)] = (short)f2bf(wpo[t]);
    }
    // proj_in 64x64 -> A-frags
    for (int t = tid; t < 64 * 64; t += nt) {
        int o = t >> 6, c = t & 63;
        int fi = (o >> 4) * 2 + (c >> 5);
        int ln = ((c >> 3) & 3) * 16 + (o & 15);
        wpiA[fi * 512 + ln * 8 + (c & 7)] = (short)f2bf(wpi[t]);
    }

    // ---- fold wc1 @ wd + pack: one block per tap k ----
    __shared__ float wdk [64 * ROWP];
    __shared__ float wc1s[64 * ROWP];
    int k = blockIdx.x;
    int t = threadIdx.x;
#pragma unroll
    for (int r = 0; r < 16; r++) {
        int idx = t + r * 256;
        int o = idx >> 6, c = idx & 63;
        wdk [o * ROWP + c] = wd[(o * 64 + c) * KK + k];
        wc1s[o * ROWP + c] = wc1[o * 64 + c];
    }
    __syncthreads();

    int ot = (t >> 4) * 4, cb = (t & 15) * 4;
    float a[4][4];
#pragma unroll
    for (int i = 0; i < 4; i++)
#pragma unroll
        for (int j = 0; j < 4; j++) a[i][j] = 0.f;
    for (int o = 0; o < 64; o++) {
        float wv_[4], sv_[4];
#pragma unroll
        for (int i = 0; i < 4; i++) wv_[i] = wc1s[(ot + i) * ROWP + o];
#pragma unroll
        for (int j = 0; j < 4; j++) sv_[j] = wdk[o * ROWP + cb + j];
#pragma unroll
        for (int i = 0; i < 4; i++)
#pragma unroll
            for (int j = 0; j < 4; j++) a[i][j] += wv_[i] * sv_[j];
    }
#pragma unroll
    for (int i = 0; i < 4; i++)
#pragma unroll
        for (int j = 0; j < 4; j++) {
            int o2 = ot + i, c = cb + j;
            int tt = o2 >> 4, m = o2 & 15;
            int kt = c >> 5, q = (c >> 3) & 3, jj = c & 7;
            int ln = q * 16 + m;
            wA[(k * 8 + tt * 2 + kt) * 512 + ln * 8 + jj] = (short)f2bf(a[i][j]);
        }
}

// ---------------------------------------------------------------------------
// k_trans: enc [c][p] -> encP [p][c]
// ---------------------------------------------------------------------------
__global__ __launch_bounds__(256) void k_trans(
    const float* __restrict__ enc, float* __restrict__ encP)
{
    __shared__ float s[64 * 65];
    int t = threadIdx.x;
    int base = blockIdx.x * 64;
#pragma unroll
    for (int r = 0; r < 16; r++) {
        int idx = t + r * 256;
        int p = idx & 63, c = idx >> 6;
        s[p * 65 + c] = enc[c * HWSZ + base + p];
    }
    __syncthreads();
#pragma unroll
    for (int r = 0; r < 16; r++) {
        int idx = t + r * 256;
        int c = idx & 63, p = idx >> 6;
        encP[(base + p) * 64 + c] = s[p * 65 + c];
    }
}

// ---------------------------------------------------------------------------
// k_deform: barrier-free MFMA deformable conv, depth-1 software pipeline.
// Per iteration: blend(k) [consumes corners(k)] -> LDS bounce -> issue
// corners(k+1) [reuses regs] -> issue off(k+2) -> MFMA(k) -> issue af(k+1).
// Gather latency overlaps a full iteration instead of ~20 instructions.
// ---------------------------------------------------------------------------
__global__ __launch_bounds__(256, 3) void k_deform(
    const float* __restrict__ encP, const float* __restrict__ off,
    const float* __restrict__ msk, const short* __restrict__ wA,
    float* __restrict__ rev)
{
    __shared__ __align__(16) short sm[4][16 * SROW];  // per-wave private

    int t = threadIdx.x;
    int lane = t & 63, w = t >> 6;
    int b = blockIdx.x;
    int xcd = b & 7, blk = b >> 3;
    int gy  = xcd * 24 + blk / 3;
    int gx0 = (blk % 3) * 64 + w * 16;

    int sp = lane >> 2, g = lane & 3;
    int sgx  = gx0 + sp;
    int gp_s = gy * WW + sgx;
    int n = lane & 15, q = lane >> 4;
    int gp_m = gy * WW + gx0 + n;
    short* smw = &sm[w][0];

    f32x4 acc[4];
#pragma unroll
    for (int ot = 0; ot < 4; ot++) acc[ot] = (f32x4){0.f, 0.f, 0.f, 0.f};

    float4 c00[4], c01[4], c10[4], c11[4];
    float a00, a01, a10, a11;
    s16x8 af[8];

    auto issue_tap = [&](int kk, float dy, float dx, float mm) {
        int ky = kk / 7, kx = kk % 7;
        float y = (float)(gy  - 3 + ky) + dy;
        float x = (float)(sgx - 3 + kx) + dx;
        float y0f = floorf(y), x0f = floorf(x);
        float wy = y - y0f, wx = x - x0f;
        int iy0 = (int)y0f, ix0 = (int)x0f;
        int iy1 = iy0 + 1, ix1 = ix0 + 1;
        bool vy0 = (iy0 >= 0) & (iy0 < HH);
        bool vy1 = (iy1 >= 0) & (iy1 < HH);
        bool vx0 = (ix0 >= 0) & (ix0 < WW);
        bool vx1 = (ix1 >= 0) & (ix1 < WW);
        int iy0c = min(max(iy0, 0), HH - 1), iy1c = min(max(iy1, 0), HH - 1);
        int ix0c = min(max(ix0, 0), WW - 1), ix1c = min(max(ix1, 0), WW - 1);
        a00 = (vy0 & vx0) ? (1.f - wy) * (1.f - wx) * mm : 0.f;
        a01 = (vy0 & vx1) ? (1.f - wy) * wx * mm : 0.f;
        a10 = (vy1 & vx0) ? wy * (1.f - wx) * mm : 0.f;
        a11 = (vy1 & vx1) ? wy * wx * mm : 0.f;
        const float4* p00 = (const float4*)(encP + (iy0c * WW + ix0c) * 64 + g * 16);
        const float4* p01 = (const float4*)(encP + (iy0c * WW + ix1c) * 64 + g * 16);
        const float4* p10 = (const float4*)(encP + (iy1c * WW + ix0c) * 64 + g * 16);
        const float4* p11 = (const float4*)(encP + (iy1c * WW + ix1c) * 64 + g * 16);
#pragma unroll
        for (int i = 0; i < 4; i++) {
            c00[i] = p00[i]; c01[i] = p01[i];
            c10[i] = p10[i]; c11[i] = p11[i];
        }
    };

    // prologue: off(0) -> corners(0); af(0); off(1)
    {
        float d0 = off[gp_s], d1 = off[HWSZ + gp_s], m0 = msk[gp_s];
        issue_tap(0, d0, d1, m0);
    }
#pragma unroll
    for (int f = 0; f < 8; f++) af[f] = *(const s16x8*)&wA[f * 512 + lane * 8];
    float dyn = off[2 * HWSZ + gp_s];
    float dxn = off[3 * HWSZ + gp_s];
    float mmn = msk[HWSZ + gp_s];

#pragma unroll 1
    for (int k = 0; k < KK; k++) {
        // blend(k): last read of corners(k)
        unsigned pk[8];
#pragma unroll
        for (int i = 0; i < 4; i++) {
            float f0 = a00 * c00[i].x + a01 * c01[i].x + a10 * c10[i].x + a11 * c11[i].x;
            float f1 = a00 * c00[i].y + a01 * c01[i].y + a10 * c10[i].y + a11 * c11[i].y;
            float f2 = a00 * c00[i].z + a01 * c01[i].z + a10 * c10[i].z + a11 * c11[i].z;
            float f3 = a00 * c00[i].w + a01 * c01[i].w + a10 * c10[i].w + a11 * c11[i].w;
            pk[2 * i]     = pkbf(f0, f1);
            pk[2 * i + 1] = pkbf(f2, f3);
        }
        *(uint4*)&smw[sp * SROW + g * 16]     = make_uint4(pk[0], pk[1], pk[2], pk[3]);
        *(uint4*)&smw[sp * SROW + g * 16 + 8] = make_uint4(pk[4], pk[5], pk[6], pk[7]);

        // issue corners(k+1) into the (now dead) corner regs
        int kk = min(k + 1, KK - 1);
        issue_tap(kk, dyn, dxn, mmn);

        // issue off(k+2)
        int k2 = min(k + 2, KK - 1);
        float dy2 = off[(2 * k2) * HWSZ + gp_s];
        float dx2 = off[(2 * k2 + 1) * HWSZ + gp_s];
        float mm2 = msk[k2 * HWSZ + gp_s];

        // B-frags (same-wave LDS bounce, lgkm only)
        s16x8 b0 = *(const s16x8*)&smw[n * SROW +  0 + q * 8];
        s16x8 b1 = *(const s16x8*)&smw[n * SROW + 32 + q * 8];

#pragma unroll
        for (int ot = 0; ot < 4; ot++) {
            acc[ot] = __builtin_amdgcn_mfma_f32_16x16x32_bf16(af[ot * 2],     b0, acc[ot], 0, 0, 0);
            acc[ot] = __builtin_amdgcn_mfma_f32_16x16x32_bf16(af[ot * 2 + 1], b1, acc[ot], 0, 0, 0);
        }
        // af(k+1) after last use of af(k)
#pragma unroll
        for (int f = 0; f < 8; f++)
            af[f] = *(const s16x8*)&wA[(kk * 8 + f) * 512 + lane * 8];

        dyn = dy2; dxn = dx2; mmn = mm2;
    }

    // epilogue: lane (q,n) holds o = ot*16 + q*4 + r for pixel n
#pragma unroll
    for (int ot = 0; ot < 4; ot++) {
        float4 rv = make_float4(acc[ot][0], acc[ot][1], acc[ot][2], acc[ot][3]);
        *(float4*)&rev[gp_m * 64 + ot * 16 + q * 4] = rv;
    }
}

// ---------------------------------------------------------------------------
// k_fft: per 8x8 patch: proj_in via MFMA bf16 (A-frags from wpiA), then
// per-channel circular conv in fp32.
// ---------------------------------------------------------------------------
__global__ __launch_bounds__(256) void k_fft(
    const float* __restrict__ encPg, const short* __restrict__ wpiA,
    const float* __restrict__ krT, float* __restrict__ e1)
{
    __shared__ __align__(16) short sbf[64 * SROW];   // bf16 enc [px][c]
    __shared__ __align__(16) float e0[64 * ROWP];    // fp32 [px][o]
    int t = threadIdx.x;
    int pbx = blockIdx.x % 24, pby = blockIdx.x / 24;
    int gx0 = pbx * 8, gy0 = pby * 8;

#pragma unroll
    for (int r = 0; r < 4; r++) {
        int idx = t + r * 256;
        int px = idx >> 4, g = idx & 15;
        int gy = gy0 + (px >> 3), gx = gx0 + (px & 7);
        float4 v = *(const float4*)&encPg[(gy * WW + gx) * 64 + g * 4];
        *(uint2*)&sbf[px * SROW + g * 4] = make_uint2(pkbf(v.x, v.y), pkbf(v.z, v.w));
    }
    __syncthreads();

    int lane = t & 63, w = t >> 6;
    int n = lane & 15, q = lane >> 4;
    s16x8 a0 = *(const s16x8*)&wpiA[(w * 2 + 0) * 512 + lane * 8];
    s16x8 a1 = *(const s16x8*)&wpiA[(w * 2 + 1) * 512 + lane * 8];
#pragma unroll
    for (int j = 0; j < 4; j++) {
        s16x8 b0 = *(const s16x8*)&sbf[(j * 16 + n) * SROW +  0 + q * 8];
        s16x8 b1 = *(const s16x8*)&sbf[(j * 16 + n) * SROW + 32 + q * 8];
        f32x4 acc = {0.f, 0.f, 0.f, 0.f};
        acc = __builtin_amdgcn_mfma_f32_16x16x32_bf16(a0, b0, acc, 0, 0, 0);
        acc = __builtin_amdgcn_mfma_f32_16x16x32_bf16(a1, b1, acc, 0, 0, 0);
#pragma unroll
        for (int r = 0; r < 4; r++)
            e0[(j * 16 + n) * ROWP + w * 16 + q * 4 + r] = acc[r];
    }
    __syncthreads();

    // circular conv: out[y][x] = sum_{u,v} kr[u][v] * e0[(y-u)%8][(x-v)%8]
    int o = t & 63;
    int yb = t >> 6;
#pragma unroll
    for (int yy = 0; yy < 2; yy++) {
        int y = yb + yy * 4;
        float outr[8];
#pragma unroll
        for (int x = 0; x < 8; x++) outr[x] = 0.f;
#pragma unroll
        for (int u = 0; u < 8; u++) {
            int ry = (y - u + 8) & 7;
            float row[8];
#pragma unroll
            for (int rx = 0; rx < 8; rx++)
                row[rx] = e0[(ry * 8 + rx) * ROWP + o];
#pragma unroll
            for (int v = 0; v < 8; v++) {
                float kv = krT[(u * 8 + v) * 64 + o];
#pragma unroll
                for (int x = 0; x < 8; x++)
                    outr[x] += kv * row[(x - v + 8) & 7];
            }
        }
        int gy = gy0 + y;
#pragma unroll
        for (int x = 0; x < 8; x++)
            e1[(gy * WW + gx0 + x) * 64 + o] = outr[x];
    }
}

// ---------------------------------------------------------------------------
// k_conv3: e3 = conv3x3(e1 + rev, pad 1) via MFMA bf16, barrier-free.
// Wave = 16x1 px strip; stages its own 3x18 halo (e1+rev, bf16) then
// 9 taps x (2 ds_read_b128 + 8 MFMA). Weights from w2A A-frags (L2-hot).
// ---------------------------------------------------------------------------
__global__ __launch_bounds__(256) void k_conv3(
    const float* __restrict__ e1, const float* __restrict__ rev,
    const short* __restrict__ w2A, float* __restrict__ e3)
{
    __shared__ __align__(16) short sm[4][54 * C3ROW];  // per-wave: 3 rows x 18 px
    int t = threadIdx.x;
    int lane = t & 63, w = t >> 6;
    int b = blockIdx.x;
    int xcd = b & 7, blk = b >> 3;
    int gy  = xcd * 24 + blk / 3;
    int gx0 = (blk % 3) * 64 + w * 16;
    short* smw = &sm[w][0];

    // stage halo: 54 rp x 16 float4-groups = 864 units over 64 lanes
    for (int r = 0; r < 14; r++) {
        int u = lane + r * 64;
        if (u < 864) {
            int rp = u >> 4, g = u & 15;
            int row = rp / 18, pxl = rp - row * 18;
            int gyy = gy + row - 1, gxx = gx0 + pxl - 1;
            float4 v = make_float4(0.f, 0.f, 0.f, 0.f);
            if (gyy >= 0 && gyy < HH && gxx >= 0 && gxx < WW) {
                int gp = (gyy * WW + gxx) * 64 + g * 4;
                float4 va = *(const float4*)&e1[gp];
                float4 vb = *(const float4*)&rev[gp];
                v.x = va.x + vb.x; v.y = va.y + vb.y;
                v.z = va.z + vb.z; v.w = va.w + vb.w;
            }
            *(uint2*)&smw[rp * C3ROW + g * 4] = make_uint2(pkbf(v.x, v.y), pkbf(v.z, v.w));
        }
    }

    int n = lane & 15, q = lane >> 4;
    f32x4 acc[4];
#pragma unroll
    for (int ot = 0; ot < 4; ot++) acc[ot] = (f32x4){0.f, 0.f, 0.f, 0.f};

#pragma unroll 1
    for (int tap = 0; tap < 9; tap++) {
        int dy = tap / 3, dx = tap - dy * 3;
        int rp = dy * 18 + n + dx;
        s16x8 b0 = *(const s16x8*)&smw[rp * C3ROW +  0 + q * 8];
        s16x8 b1 = *(const s16x8*)&smw[rp * C3ROW + 32 + q * 8];
#pragma unroll
        for (int ot = 0; ot < 4; ot++) {
            s16x8 a0 = *(const s16x8*)&w2A[(tap * 8 + ot * 2 + 0) * 512 + lane * 8];
            s16x8 a1 = *(const s16x8*)&w2A[(tap * 8 + ot * 2 + 1) * 512 + lane * 8];
            acc[ot] = __builtin_amdgcn_mfma_f32_16x16x32_bf16(a0, b0, acc[ot], 0, 0, 0);
            acc[ot] = __builtin_amdgcn_mfma_f32_16x16x32_bf16(a1, b1, acc[ot], 0, 0, 0);
        }
    }
    int gp_m = gy * WW + gx0 + n;
#pragma unroll
    for (int ot = 0; ot < 4; ot++) {
        float4 rv = make_float4(acc[ot][0], acc[ot][1], acc[ot][2], acc[ot][3]);
        *(float4*)&e3[gp_m * 64 + ot * 16 + q * 4] = rv;
    }
}

// ---------------------------------------------------------------------------
// k_out: feat = [e3 ; dec], g = wpo @ feat (128->128) via MFMA bf16,
// out = g[:64] * g[64:]. Barrier-free, wave = 16 px strip.
// ---------------------------------------------------------------------------
__global__ __launch_bounds__(256) void k_out(
    const float* __restrict__ e3, const float* __restrict__ dec,
    const short* __restrict__ wpoA, float* __restrict__ out)
{
    __shared__ __align__(16) short sm[4][16 * OROW];
    int t = threadIdx.x;
    int lane = t & 63, w = t >> 6;
    int b = blockIdx.x;
    int xcd = b & 7, blk = b >> 3;
    int gy  = xcd * 24 + blk / 3;
    int gx0 = (blk % 3) * 64 + w * 16;
    short* smw = &sm[w][0];
    int n = lane & 15, q = lane >> 4;

    // e3 half: [px][0..64), coalesced float4
#pragma unroll
    for (int r = 0; r < 4; r++) {
        int u = lane + r * 64;
        int px = u >> 4, g = u & 15;
        float4 v = *(const float4*)&e3[(gy * WW + gx0 + px) * 64 + g * 4];
        *(uint2*)&smw[px * OROW + g * 4] = make_uint2(pkbf(v.x, v.y), pkbf(v.z, v.w));
    }
    // dec half: [px][64..128), channel-major source (64B-coalesced per inst)
    {
        int gp = gy * WW + gx0 + n;
        unsigned pk[8];
#pragma unroll
        for (int i = 0; i < 8; i++) {
            float va = dec[(q * 16 + 2 * i)     * HWSZ + gp];
            float vb = dec[(q * 16 + 2 * i + 1) * HWSZ + gp];
            pk[i] = pkbf(va, vb);
        }
        *(uint4*)&smw[n * OROW + 64 + q * 16]     = make_uint4(pk[0], pk[1], pk[2], pk[3]);
        *(uint4*)&smw[n * OROW + 64 + q * 16 + 8] = make_uint4(pk[4], pk[5], pk[6], pk[7]);
    }

    f32x4 acc[8];
#pragma unroll
    for (int ot = 0; ot < 8; ot++) acc[ot] = (f32x4){0.f, 0.f, 0.f, 0.f};

#pragma unroll 1
    for (int kt = 0; kt < 4; kt++) {
        s16x8 bb = *(const s16x8*)&smw[n * OROW + kt * 32 + q * 8];
#pragma unroll
        for (int ot = 0; ot < 8; ot++) {
            s16x8 aa = *(const s16x8*)&wpoA[(ot * 4 + kt) * 512 + lane * 8];
            acc[ot] = __builtin_amdgcn_mfma_f32_16x16x32_bf16(aa, bb, acc[ot], 0, 0, 0);
        }
    }

    int gp = gy * WW + gx0 + n;
#pragma unroll
    for (int ot = 0; ot < 4; ot++)
#pragma unroll
        for (int r = 0; r < 4; r++)
            out[(ot * 16 + q * 4 + r) * HWSZ + gp] = acc[ot][r] * acc[ot + 4][r];
}

// ---------------------------------------------------------------------------
extern "C" void kernel_launch(void* const* d_in, const int* in_sizes, int n_in,
                              void* d_out, int out_size, void* d_ws, size_t ws_size,
                              hipStream_t stream)
{
    const float* enc  = (const float*)d_in[0];
    const float* dec  = (const float*)d_in[1];
    const float* ioff = (const float*)d_in[2];
    const float* iwt  = (const float*)d_in[3];
    const float* wpi  = (const float*)d_in[4];
    const float* fw   = (const float*)d_in[5];
    const float* wpo  = (const float*)d_in[6];
    const float* wd   = (const float*)d_in[7];
    const float* wc1  = (const float*)d_in[8];
    const float* wc2  = (const float*)d_in[9];
    float* out = (float*)d_out;
    float* ws  = (float*)d_ws;

    float* krT  = ws;                       //    4096
    float* rev  = ws + 4096;                // 2359296  [px][64]
    float* e1   = ws + 2363392;             // 2359296  [px][64]
    float* e3   = ws + 4722688;             // 2359296  [px][64]
    float* encP = ws + 7081984;             // 2359296  [px][64]
    short* wA   = (short*)(ws + 9441280);   // 200704 bf16
    short* w2A  = (short*)(ws + 9541632);   //  36864 bf16
    short* wpoA = (short*)(ws + 9560064);   //  16384 bf16
    short* wpiA = (short*)(ws + 9568256);   //   4096 bf16
    // total 9570304 floats = 38.3 MB

    hipLaunchKernelGGL(k_prep,   dim3(49),  dim3(256), 0, stream,
                       fw, wd, wc2, wc1, wpo, wpi, krT, wA, w2A, wpoA, wpiA);
    hipLaunchKernelGGL(k_trans,  dim3(576), dim3(256), 0, stream, enc, encP);
    hipLaunchKernelGGL(k_deform, dim3(576), dim3(256), 0, stream, encP, ioff, iwt, wA, rev);
    hipLaunchKernelGGL(k_fft,    dim3(576), dim3(256), 0, stream, encP, wpiA, krT, e1);
    hipLaunchKernelGGL(k_conv3,  dim3(576), dim3(256), 0, stream, e1, rev, w2A, e3);
    hipLaunchKernelGGL(k_out,    dim3(576), dim3(256), 0, stream, e3, dec, wpoA, out);
}

// Round 7
// 289.879 us; speedup vs baseline: 37.2088x; 1.1833x over previous
//
#include <hip/hip_runtime.h>
#include <math.h>

#define CH    64
#define WW    192
#define HH    192
#define HWSZ  (192*192)
#define KK    49
#define ROWP  68   // padded fp32 LDS row (dwords)
#define SROW  72   // bf16 row stride in shorts (144B)
#define C3ROW 72   // conv3 staged px stride (shorts)
#define OROW  136  // k_out staged px stride (shorts, 128ch + 8 pad)

typedef __attribute__((ext_vector_type(8))) short s16x8;   // 8 bf16 = 4 VGPR
typedef __attribute__((ext_vector_type(4))) float f32x4;

__device__ __forceinline__ unsigned short f2bf(float f) {
    union { float f; unsigned u; } v; v.f = f;
    unsigned u = v.u + 0x7FFFu + ((v.u >> 16) & 1u);   // RNE
    return (unsigned short)(u >> 16);
}

// pack two floats to bf16x2 (round-half-up): 2 adds + 1 v_perm
__device__ __forceinline__ unsigned pkbf(float lo, float hi) {
    return __builtin_amdgcn_perm(__float_as_uint(hi) + 0x8000u,
                                 __float_as_uint(lo) + 0x8000u, 0x07060302u);
}

// ---------------------------------------------------------------------------
// k_prep (grid 49 x 256): krT + A-fragment packs (wA, w2A, wpoA, wpiA)
// ---------------------------------------------------------------------------
__device__ const float c_cos8[8] = {
    1.f, 0.70710678118654752f, 0.f, -0.70710678118654752f,
   -1.f, -0.70710678118654752f, 0.f, 0.70710678118654752f };

__global__ __launch_bounds__(256) void k_prep(
    const float* __restrict__ fw,   // [64,1,1,8,5]
    const float* __restrict__ wd,   // [64,64,7,7]
    const float* __restrict__ w2,   // [64,64,3,3]
    const float* __restrict__ wc1,  // [64,64,1,1]
    const float* __restrict__ wpo,  // [128,128]
    const float* __restrict__ wpi,  // [64,64]
    float* __restrict__ krT,        // [64 uv][64 c]
    short* __restrict__ wA,         // [49*8*512]
    short* __restrict__ w2A,        // [9*8*512]
    short* __restrict__ wpoA,       // [32*512]
    short* __restrict__ wpiA)       // [8*512]
{
    int tid = blockIdx.x * blockDim.x + threadIdx.x;
    int nt  = gridDim.x * blockDim.x;
    for (int t = tid; t < 64 * 64; t += nt) {
        int uv = t >> 6, c = t & 63;
        int u = uv >> 3, v = uv & 7;
        float acc = 0.f;
        for (int ky = 0; ky < 8; ky++)
            for (int kx = 0; kx < 8; kx++) {
                float wv = (kx <= 4) ? fw[c * 40 + ky * 5 + kx]
                                     : fw[c * 40 + ((8 - ky) & 7) * 5 + (8 - kx)];
                acc += wv * c_cos8[(ky * u + kx * v) & 7];
            }
        krT[uv * 64 + c] = acc * (1.f / 64.f);
    }
    // conv3 weights -> A-frags (tap-major)
    for (int t = tid; t < 9 * 4096; t += nt) {
        int tap = t / 4096, rem = t & 4095;
        int o = rem >> 6, c = rem & 63;
        float v = w2[(o * 64 + c) * 9 + tap];
        int fi = tap * 8 + (o >> 4) * 2 + (c >> 5);
        int ln = ((c >> 3) & 3) * 16 + (o & 15);
        w2A[fi * 512 + ln * 8 + (c & 7)] = (short)f2bf(v);
    }
    // proj_out 128x128 -> A-frags
    for (int t = tid; t < 128 * 128; t += nt) {
        int o = t >> 7, c = t & 127;
        int fi = (o >> 4) * 4 + (c >> 5);
        int ln = ((c >> 3) & 3) * 16 + (o & 15);
        wpoA[fi * 512 + ln * 8 + (c & 7)] = (short)f2bf(wpo[t]);
    }
    // proj_in 64x64 -> A-frags
    for (int t = tid; t < 64 * 64; t += nt) {
        int o = t >> 6, c = t & 63;
        int fi = (o >> 4) * 2 + (c >> 5);
        int ln = ((c >> 3) & 3) * 16 + (o & 15);
        wpiA[fi * 512 + ln * 8 + (c & 7)] = (short)f2bf(wpi[t]);
    }

    // ---- fold wc1 @ wd + pack: one block per tap k ----
    __shared__ float wdk [64 * ROWP];
    __shared__ float wc1s[64 * ROWP];
    int k = blockIdx.x;
    int t = threadIdx.x;
#pragma unroll
    for (int r = 0; r < 16; r++) {
        int idx = t + r * 256;
        int o = idx >> 6, c = idx & 63;
        wdk [o * ROWP + c] = wd[(o * 64 + c) * KK + k];
        wc1s[o * ROWP + c] = wc1[o * 64 + c];
    }
    __syncthreads();

    int ot = (t >> 4) * 4, cb = (t & 15) * 4;
    float a[4][4];
#pragma unroll
    for (int i = 0; i < 4; i++)
#pragma unroll
        for (int j = 0; j < 4; j++) a[i][j] = 0.f;
    for (int o = 0; o < 64; o++) {
        float wv_[4], sv_[4];
#pragma unroll
        for (int i = 0; i < 4; i++) wv_[i] = wc1s[(ot + i) * ROWP + o];
#pragma unroll
        for (int j = 0; j < 4; j++) sv_[j] = wdk[o * ROWP + cb + j];
#pragma unroll
        for (int i = 0; i < 4; i++)
#pragma unroll
            for (int j = 0; j < 4; j++) a[i][j] += wv_[i] * sv_[j];
    }
#pragma unroll
    for (int i = 0; i < 4; i++)
#pragma unroll
        for (int j = 0; j < 4; j++) {
            int o2 = ot + i, c = cb + j;
            int tt = o2 >> 4, m = o2 & 15;
            int kt = c >> 5, q = (c >> 3) & 3, jj = c & 7;
            int ln = q * 16 + m;
            wA[(k * 8 + tt * 2 + kt) * 512 + ln * 8 + jj] = (short)f2bf(a[i][j]);
        }
}

// ---------------------------------------------------------------------------
// k_trans: enc [c][p] -> encP [p][c]
// ---------------------------------------------------------------------------
__global__ __launch_bounds__(256) void k_trans(
    const float* __restrict__ enc, float* __restrict__ encP)
{
    __shared__ float s[64 * 65];
    int t = threadIdx.x;
    int base = blockIdx.x * 64;
#pragma unroll
    for (int r = 0; r < 16; r++) {
        int idx = t + r * 256;
        int p = idx & 63, c = idx >> 6;
        s[p * 65 + c] = enc[c * HWSZ + base + p];
    }
    __syncthreads();
#pragma unroll
    for (int r = 0; r < 16; r++) {
        int idx = t + r * 256;
        int c = idx & 63, p = idx >> 6;
        encP[(base + p) * 64 + c] = s[p * 65 + c];
    }
}

// ---------------------------------------------------------------------------
// k_deform: MFMA deformable conv, K-split across waves for TLP.
// Block = one 16x1 px strip, 2304 blocks. Wave w handles taps
// [0,13) / [13,25) / [25,37) / [37,49); per tap: gather corners (coalesced
// 256B per 4-lane group), blend, wave-private LDS bounce (no barrier),
// 8 MFMAs. End: one __syncthreads + LDS reduction (wave 0 sums & stores).
// ---------------------------------------------------------------------------
#define REDW 20   // reduction row stride (floats): 80B, 16B-aligned

__global__ __launch_bounds__(256) void k_deform(
    const float* __restrict__ encP, const float* __restrict__ off,
    const float* __restrict__ msk, const short* __restrict__ wA,
    float* __restrict__ rev)
{
    __shared__ __align__(16) short sm[4][16 * SROW];  // per-wave bounce
    __shared__ __align__(16) float red[3 * 64 * REDW];

    int t = threadIdx.x;
    int lane = t & 63, w = t >> 6;
    int b = blockIdx.x;
    int xcd = b & 7, blk = b >> 3;          // 288 strips per xcd band
    int gy  = xcd * 24 + blk / 12;
    int gx0 = (blk % 12) * 16;

    int sp = lane >> 2, g = lane & 3;
    int sgx  = gx0 + sp;
    int gp_s = gy * WW + sgx;
    int n = lane & 15, q = lane >> 4;
    short* smw = &sm[w][0];

    f32x4 acc[4];
#pragma unroll
    for (int ot = 0; ot < 4; ot++) acc[ot] = (f32x4){0.f, 0.f, 0.f, 0.f};

    int kstart = (w == 0) ? 0 : 13 + (w - 1) * 12;
    int kend   = (w == 0) ? 13 : kstart + 12;

    float dy = off[(2 * kstart) * HWSZ + gp_s];
    float dx = off[(2 * kstart + 1) * HWSZ + gp_s];
    float mm = msk[kstart * HWSZ + gp_s];

#pragma unroll 1
    for (int k = kstart; k < kend; k++) {
        int ky = k / 7, kx = k % 7;
        float y = (float)(gy  - 3 + ky) + dy;
        float x = (float)(sgx - 3 + kx) + dx;
        float y0f = floorf(y), x0f = floorf(x);
        float wy = y - y0f, wx = x - x0f;
        int iy0 = (int)y0f, ix0 = (int)x0f;
        int iy1 = iy0 + 1, ix1 = ix0 + 1;
        bool vy0 = (iy0 >= 0) & (iy0 < HH);
        bool vy1 = (iy1 >= 0) & (iy1 < HH);
        bool vx0 = (ix0 >= 0) & (ix0 < WW);
        bool vx1 = (ix1 >= 0) & (ix1 < WW);
        int iy0c = min(max(iy0, 0), HH - 1), iy1c = min(max(iy1, 0), HH - 1);
        int ix0c = min(max(ix0, 0), WW - 1), ix1c = min(max(ix1, 0), WW - 1);
        float a00 = (vy0 & vx0) ? (1.f - wy) * (1.f - wx) * mm : 0.f;
        float a01 = (vy0 & vx1) ? (1.f - wy) * wx * mm : 0.f;
        float a10 = (vy1 & vx0) ? wy * (1.f - wx) * mm : 0.f;
        float a11 = (vy1 & vx1) ? wy * wx * mm : 0.f;

        const float4* p00 = (const float4*)(encP + (iy0c * WW + ix0c) * 64 + g * 16);
        const float4* p01 = (const float4*)(encP + (iy0c * WW + ix1c) * 64 + g * 16);
        const float4* p10 = (const float4*)(encP + (iy1c * WW + ix0c) * 64 + g * 16);
        const float4* p11 = (const float4*)(encP + (iy1c * WW + ix1c) * 64 + g * 16);
        float4 c00[4], c01[4], c10[4], c11[4];
#pragma unroll
        for (int i = 0; i < 4; i++) {
            c00[i] = p00[i]; c01[i] = p01[i];
            c10[i] = p10[i]; c11[i] = p11[i];
        }

        // prefetch next-tap offsets
        float dyn = 0.f, dxn = 0.f, mmn = 0.f;
        if (k + 1 < kend) {
            dyn = off[(2 * k + 2) * HWSZ + gp_s];
            dxn = off[(2 * k + 3) * HWSZ + gp_s];
            mmn = msk[(k + 1) * HWSZ + gp_s];
        }

        // A-frag loads (L2-hot, independent of samples)
        s16x8 af[8];
#pragma unroll
        for (int f = 0; f < 8; f++)
            af[f] = *(const s16x8*)&wA[(k * 8 + f) * 512 + lane * 8];

        // blend + pack bf16 + wave-private LDS bounce
        unsigned pk[8];
#pragma unroll
        for (int i = 0; i < 4; i++) {
            float f0 = a00 * c00[i].x + a01 * c01[i].x + a10 * c10[i].x + a11 * c11[i].x;
            float f1 = a00 * c00[i].y + a01 * c01[i].y + a10 * c10[i].y + a11 * c11[i].y;
            float f2 = a00 * c00[i].z + a01 * c01[i].z + a10 * c10[i].z + a11 * c11[i].z;
            float f3 = a00 * c00[i].w + a01 * c01[i].w + a10 * c10[i].w + a11 * c11[i].w;
            pk[2 * i]     = pkbf(f0, f1);
            pk[2 * i + 1] = pkbf(f2, f3);
        }
        *(uint4*)&smw[sp * SROW + g * 16]     = make_uint4(pk[0], pk[1], pk[2], pk[3]);
        *(uint4*)&smw[sp * SROW + g * 16 + 8] = make_uint4(pk[4], pk[5], pk[6], pk[7]);

        s16x8 b0 = *(const s16x8*)&smw[n * SROW +  0 + q * 8];
        s16x8 b1 = *(const s16x8*)&smw[n * SROW + 32 + q * 8];

#pragma unroll
        for (int ot = 0; ot < 4; ot++) {
            acc[ot] = __builtin_amdgcn_mfma_f32_16x16x32_bf16(af[ot * 2],     b0, acc[ot], 0, 0, 0);
            acc[ot] = __builtin_amdgcn_mfma_f32_16x16x32_bf16(af[ot * 2 + 1], b1, acc[ot], 0, 0, 0);
        }

        dy = dyn; dx = dxn; mm = mmn;
    }

    // cross-wave reduction: waves 1-3 export, wave 0 sums + stores
    if (w > 0) {
        float* rp = &red[(w - 1) * 64 * REDW + lane * REDW];
#pragma unroll
        for (int ot = 0; ot < 4; ot++)
            *(float4*)&rp[ot * 4] = make_float4(acc[ot][0], acc[ot][1], acc[ot][2], acc[ot][3]);
    }
    __syncthreads();
    if (w == 0) {
#pragma unroll
        for (int ww = 0; ww < 3; ww++) {
            const float* rp = &red[ww * 64 * REDW + lane * REDW];
#pragma unroll
            for (int ot = 0; ot < 4; ot++) {
                float4 v = *(const float4*)&rp[ot * 4];
                acc[ot][0] += v.x; acc[ot][1] += v.y;
                acc[ot][2] += v.z; acc[ot][3] += v.w;
            }
        }
        int gp_m = gy * WW + gx0 + n;
#pragma unroll
        for (int ot = 0; ot < 4; ot++) {
            float4 rv = make_float4(acc[ot][0], acc[ot][1], acc[ot][2], acc[ot][3]);
            *(float4*)&rev[gp_m * 64 + ot * 16 + q * 4] = rv;
        }
    }
}

// ---------------------------------------------------------------------------
// k_fft: per 8x8 patch: proj_in via MFMA bf16, then circular conv (fp32).
// ---------------------------------------------------------------------------
__global__ __launch_bounds__(256) void k_fft(
    const float* __restrict__ encPg, const short* __restrict__ wpiA,
    const float* __restrict__ krT, float* __restrict__ e1)
{
    __shared__ __align__(16) short sbf[64 * SROW];   // bf16 enc [px][c]
    __shared__ __align__(16) float e0[64 * ROWP];    // fp32 [px][o]
    int t = threadIdx.x;
    int pbx = blockIdx.x % 24, pby = blockIdx.x / 24;
    int gx0 = pbx * 8, gy0 = pby * 8;

#pragma unroll
    for (int r = 0; r < 4; r++) {
        int idx = t + r * 256;
        int px = idx >> 4, g = idx & 15;
        int gy = gy0 + (px >> 3), gx = gx0 + (px & 7);
        float4 v = *(const float4*)&encPg[(gy * WW + gx) * 64 + g * 4];
        *(uint2*)&sbf[px * SROW + g * 4] = make_uint2(pkbf(v.x, v.y), pkbf(v.z, v.w));
    }
    __syncthreads();

    int lane = t & 63, w = t >> 6;
    int n = lane & 15, q = lane >> 4;
    s16x8 a0 = *(const s16x8*)&wpiA[(w * 2 + 0) * 512 + lane * 8];
    s16x8 a1 = *(const s16x8*)&wpiA[(w * 2 + 1) * 512 + lane * 8];
#pragma unroll
    for (int j = 0; j < 4; j++) {
        s16x8 b0 = *(const s16x8*)&sbf[(j * 16 + n) * SROW +  0 + q * 8];
        s16x8 b1 = *(const s16x8*)&sbf[(j * 16 + n) * SROW + 32 + q * 8];
        f32x4 acc = {0.f, 0.f, 0.f, 0.f};
        acc = __builtin_amdgcn_mfma_f32_16x16x32_bf16(a0, b0, acc, 0, 0, 0);
        acc = __builtin_amdgcn_mfma_f32_16x16x32_bf16(a1, b1, acc, 0, 0, 0);
#pragma unroll
        for (int r = 0; r < 4; r++)
            e0[(j * 16 + n) * ROWP + w * 16 + q * 4 + r] = acc[r];
    }
    __syncthreads();

    int o = t & 63;
    int yb = t >> 6;
#pragma unroll
    for (int yy = 0; yy < 2; yy++) {
        int y = yb + yy * 4;
        float outr[8];
#pragma unroll
        for (int x = 0; x < 8; x++) outr[x] = 0.f;
#pragma unroll
        for (int u = 0; u < 8; u++) {
            int ry = (y - u + 8) & 7;
            float row[8];
#pragma unroll
            for (int rx = 0; rx < 8; rx++)
                row[rx] = e0[(ry * 8 + rx) * ROWP + o];
#pragma unroll
            for (int v = 0; v < 8; v++) {
                float kv = krT[(u * 8 + v) * 64 + o];
#pragma unroll
                for (int x = 0; x < 8; x++)
                    outr[x] += kv * row[(x - v + 8) & 7];
            }
        }
        int gy = gy0 + y;
#pragma unroll
        for (int x = 0; x < 8; x++)
            e1[(gy * WW + gx0 + x) * 64 + o] = outr[x];
    }
}

// ---------------------------------------------------------------------------
// k_conv3: e3 = conv3x3(e1 + rev, pad 1) via MFMA bf16, barrier-free.
// ---------------------------------------------------------------------------
__global__ __launch_bounds__(256) void k_conv3(
    const float* __restrict__ e1, const float* __restrict__ rev,
    const short* __restrict__ w2A, float* __restrict__ e3)
{
    __shared__ __align__(16) short sm[4][54 * C3ROW];  // per-wave: 3 rows x 18 px
    int t = threadIdx.x;
    int lane = t & 63, w = t >> 6;
    int b = blockIdx.x;
    int xcd = b & 7, blk = b >> 3;
    int gy  = xcd * 24 + blk / 3;
    int gx0 = (blk % 3) * 64 + w * 16;
    short* smw = &sm[w][0];

    for (int r = 0; r < 14; r++) {
        int u = lane + r * 64;
        if (u < 864) {
            int rp = u >> 4, g = u & 15;
            int row = rp / 18, pxl = rp - row * 18;
            int gyy = gy + row - 1, gxx = gx0 + pxl - 1;
            float4 v = make_float4(0.f, 0.f, 0.f, 0.f);
            if (gyy >= 0 && gyy < HH && gxx >= 0 && gxx < WW) {
                int gp = (gyy * WW + gxx) * 64 + g * 4;
                float4 va = *(const float4*)&e1[gp];
                float4 vb = *(const float4*)&rev[gp];
                v.x = va.x + vb.x; v.y = va.y + vb.y;
                v.z = va.z + vb.z; v.w = va.w + vb.w;
            }
            *(uint2*)&smw[rp * C3ROW + g * 4] = make_uint2(pkbf(v.x, v.y), pkbf(v.z, v.w));
        }
    }

    int n = lane & 15, q = lane >> 4;
    f32x4 acc[4];
#pragma unroll
    for (int ot = 0; ot < 4; ot++) acc[ot] = (f32x4){0.f, 0.f, 0.f, 0.f};

#pragma unroll 1
    for (int tap = 0; tap < 9; tap++) {
        int dy = tap / 3, dx = tap - dy * 3;
        int rp = dy * 18 + n + dx;
        s16x8 b0 = *(const s16x8*)&smw[rp * C3ROW +  0 + q * 8];
        s16x8 b1 = *(const s16x8*)&smw[rp * C3ROW + 32 + q * 8];
#pragma unroll
        for (int ot = 0; ot < 4; ot++) {
            s16x8 a0 = *(const s16x8*)&w2A[(tap * 8 + ot * 2 + 0) * 512 + lane * 8];
            s16x8 a1 = *(const s16x8*)&w2A[(tap * 8 + ot * 2 + 1) * 512 + lane * 8];
            acc[ot] = __builtin_amdgcn_mfma_f32_16x16x32_bf16(a0, b0, acc[ot], 0, 0, 0);
            acc[ot] = __builtin_amdgcn_mfma_f32_16x16x32_bf16(a1, b1, acc[ot], 0, 0, 0);
        }
    }
    int gp_m = gy * WW + gx0 + n;
#pragma unroll
    for (int ot = 0; ot < 4; ot++) {
        float4 rv = make_float4(acc[ot][0], acc[ot][1], acc[ot][2], acc[ot][3]);
        *(float4*)&e3[gp_m * 64 + ot * 16 + q * 4] = rv;
    }
}

// ---------------------------------------------------------------------------
// k_out: feat = [e3 ; dec], g = wpo @ feat via MFMA bf16, out = g1*g2.
// ---------------------------------------------------------------------------
__global__ __launch_bounds__(256) void k_out(
    const float* __restrict__ e3, const float* __restrict__ dec,
    const short* __restrict__ wpoA, float* __restrict__ out)
{
    __shared__ __align__(16) short sm[4][16 * OROW];
    int t = threadIdx.x;
    int lane = t & 63, w = t >> 6;
    int b = blockIdx.x;
    int xcd = b & 7, blk = b >> 3;
    int gy  = xcd * 24 + blk / 3;
    int gx0 = (blk % 3) * 64 + w * 16;
    short* smw = &sm[w][0];
    int n = lane & 15, q = lane >> 4;

#pragma unroll
    for (int r = 0; r < 4; r++) {
        int u = lane + r * 64;
        int px = u >> 4, g = u & 15;
        float4 v = *(const float4*)&e3[(gy * WW + gx0 + px) * 64 + g * 4];
        *(uint2*)&smw[px * OROW + g * 4] = make_uint2(pkbf(v.x, v.y), pkbf(v.z, v.w));
    }
    {
        int gp = gy * WW + gx0 + n;
        unsigned pk[8];
#pragma unroll
        for (int i = 0; i < 8; i++) {
            float va = dec[(q * 16 + 2 * i)     * HWSZ + gp];
            float vb = dec[(q * 16 + 2 * i + 1) * HWSZ + gp];
            pk[i] = pkbf(va, vb);
        }
        *(uint4*)&smw[n * OROW + 64 + q * 16]     = make_uint4(pk[0], pk[1], pk[2], pk[3]);
        *(uint4*)&smw[n * OROW + 64 + q * 16 + 8] = make_uint4(pk[4], pk[5], pk[6], pk[7]);
    }

    f32x4 acc[8];
#pragma unroll
    for (int ot = 0; ot < 8; ot++) acc[ot] = (f32x4){0.f, 0.f, 0.f, 0.f};

#pragma unroll 1
    for (int kt = 0; kt < 4; kt++) {
        s16x8 bb = *(const s16x8*)&smw[n * OROW + kt * 32 + q * 8];
#pragma unroll
        for (int ot = 0; ot < 8; ot++) {
            s16x8 aa = *(const s16x8*)&wpoA[(ot * 4 + kt) * 512 + lane * 8];
            acc[ot] = __builtin_amdgcn_mfma_f32_16x16x32_bf16(aa, bb, acc[ot], 0, 0, 0);
        }
    }

    int gp = gy * WW + gx0 + n;
#pragma unroll
    for (int ot = 0; ot < 4; ot++)
#pragma unroll
        for (int r = 0; r < 4; r++)
            out[(ot * 16 + q * 4 + r) * HWSZ + gp] = acc[ot][r] * acc[ot + 4][r];
}

// ---------------------------------------------------------------------------
extern "C" void kernel_launch(void* const* d_in, const int* in_sizes, int n_in,
                              void* d_out, int out_size, void* d_ws, size_t ws_size,
                              hipStream_t stream)
{
    const float* enc  = (const float*)d_in[0];
    const float* dec  = (const float*)d_in[1];
    const float* ioff = (const float*)d_in[2];
    const float* iwt  = (const float*)d_in[3];
    const float* wpi  = (const float*)d_in[4];
    const float* fw   = (const float*)d_in[5];
    const float* wpo  = (const float*)d_in[6];
    const float* wd   = (const float*)d_in[7];
    const float* wc1  = (const float*)d_in[8];
    const float* wc2  = (const float*)d_in[9];
    float* out = (float*)d_out;
    float* ws  = (float*)d_ws;

    float* krT  = ws;                       //    4096
    float* rev  = ws + 4096;                // 2359296  [px][64]
    float* e1   = ws + 2363392;             // 2359296  [px][64]
    float* e3   = ws + 4722688;             // 2359296  [px][64]
    float* encP = ws + 7081984;             // 2359296  [px][64]
    short* wA   = (short*)(ws + 9441280);   // 200704 bf16
    short* w2A  = (short*)(ws + 9541632);   //  36864 bf16
    short* wpoA = (short*)(ws + 9560064);   //  16384 bf16
    short* wpiA = (short*)(ws + 9568256);   //   4096 bf16

    hipLaunchKernelGGL(k_prep,   dim3(49),   dim3(256), 0, stream,
                       fw, wd, wc2, wc1, wpo, wpi, krT, wA, w2A, wpoA, wpiA);
    hipLaunchKernelGGL(k_trans,  dim3(576),  dim3(256), 0, stream, enc, encP);
    hipLaunchKernelGGL(k_deform, dim3(2304), dim3(256), 0, stream, encP, ioff, iwt, wA, rev);
    hipLaunchKernelGGL(k_fft,    dim3(576),  dim3(256), 0, stream, encP, wpiA, krT, e1);
    hipLaunchKernelGGL(k_conv3,  dim3(576),  dim3(256), 0, stream, e1, rev, w2A, e3);
    hipLaunchKernelGGL(k_out,    dim3(576),  dim3(256), 0, stream, e3, dec, wpoA, out);
}

// Round 8
// 284.882 us; speedup vs baseline: 37.8615x; 1.0175x over previous
//
#include <hip/hip_runtime.h>
#include <math.h>

#define CH    64
#define WW    192
#define HH    192
#define HWSZ  (192*192)
#define KK    49
#define ROWP  68   // padded fp32 LDS row (dwords)
#define SROW  72   // bf16 row stride in shorts (144B)
#define C3ROW 72   // conv3 staged px stride (shorts)
#define OROW  136  // k_out staged px stride (shorts, 128ch + 8 pad)

typedef __attribute__((ext_vector_type(8))) short s16x8;   // 8 bf16 = 4 VGPR
typedef __attribute__((ext_vector_type(4))) float f32x4;

__device__ __forceinline__ unsigned short f2bf(float f) {
    union { float f; unsigned u; } v; v.f = f;
    unsigned u = v.u + 0x7FFFu + ((v.u >> 16) & 1u);   // RNE
    return (unsigned short)(u >> 16);
}

// pack two floats to bf16x2 (round-half-up): 2 adds + 1 v_perm
__device__ __forceinline__ unsigned pkbf(float lo, float hi) {
    return __builtin_amdgcn_perm(__float_as_uint(hi) + 0x8000u,
                                 __float_as_uint(lo) + 0x8000u, 0x07060302u);
}

// ---------------------------------------------------------------------------
// k_prep (grid 49 x 256): krT + A-fragment packs (wA, w2A, wpoA, wpiA)
// ---------------------------------------------------------------------------
__device__ const float c_cos8[8] = {
    1.f, 0.70710678118654752f, 0.f, -0.70710678118654752f,
   -1.f, -0.70710678118654752f, 0.f, 0.70710678118654752f };

__global__ __launch_bounds__(256) void k_prep(
    const float* __restrict__ fw,   // [64,1,1,8,5]
    const float* __restrict__ wd,   // [64,64,7,7]
    const float* __restrict__ w2,   // [64,64,3,3]
    const float* __restrict__ wc1,  // [64,64,1,1]
    const float* __restrict__ wpo,  // [128,128]
    const float* __restrict__ wpi,  // [64,64]
    float* __restrict__ krT,        // [64 uv][64 c]
    short* __restrict__ wA,         // [49*8*512]
    short* __restrict__ w2A,        // [9*8*512]
    short* __restrict__ wpoA,       // [32*512]
    short* __restrict__ wpiA)       // [8*512]
{
    int tid = blockIdx.x * blockDim.x + threadIdx.x;
    int nt  = gridDim.x * blockDim.x;
    for (int t = tid; t < 64 * 64; t += nt) {
        int uv = t >> 6, c = t & 63;
        int u = uv >> 3, v = uv & 7;
        float acc = 0.f;
        for (int ky = 0; ky < 8; ky++)
            for (int kx = 0; kx < 8; kx++) {
                float wv = (kx <= 4) ? fw[c * 40 + ky * 5 + kx]
                                     : fw[c * 40 + ((8 - ky) & 7) * 5 + (8 - kx)];
                acc += wv * c_cos8[(ky * u + kx * v) & 7];
            }
        krT[uv * 64 + c] = acc * (1.f / 64.f);
    }
    for (int t = tid; t < 9 * 4096; t += nt) {
        int tap = t / 4096, rem = t & 4095;
        int o = rem >> 6, c = rem & 63;
        float v = w2[(o * 64 + c) * 9 + tap];
        int fi = tap * 8 + (o >> 4) * 2 + (c >> 5);
        int ln = ((c >> 3) & 3) * 16 + (o & 15);
        w2A[fi * 512 + ln * 8 + (c & 7)] = (short)f2bf(v);
    }
    for (int t = tid; t < 128 * 128; t += nt) {
        int o = t >> 7, c = t & 127;
        int fi = (o >> 4) * 4 + (c >> 5);
        int ln = ((c >> 3) & 3) * 16 + (o & 15);
        wpoA[fi * 512 + ln * 8 + (c & 7)] = (short)f2bf(wpo[t]);
    }
    for (int t = tid; t < 64 * 64; t += nt) {
        int o = t >> 6, c = t & 63;
        int fi = (o >> 4) * 2 + (c >> 5);
        int ln = ((c >> 3) & 3) * 16 + (o & 15);
        wpiA[fi * 512 + ln * 8 + (c & 7)] = (short)f2bf(wpi[t]);
    }

    // ---- fold wc1 @ wd + pack: one block per tap k ----
    __shared__ float wdk [64 * ROWP];
    __shared__ float wc1s[64 * ROWP];
    int k = blockIdx.x;
    int t = threadIdx.x;
#pragma unroll
    for (int r = 0; r < 16; r++) {
        int idx = t + r * 256;
        int o = idx >> 6, c = idx & 63;
        wdk [o * ROWP + c] = wd[(o * 64 + c) * KK + k];
        wc1s[o * ROWP + c] = wc1[o * 64 + c];
    }
    __syncthreads();

    int ot = (t >> 4) * 4, cb = (t & 15) * 4;
    float a[4][4];
#pragma unroll
    for (int i = 0; i < 4; i++)
#pragma unroll
        for (int j = 0; j < 4; j++) a[i][j] = 0.f;
    for (int o = 0; o < 64; o++) {
        float wv_[4], sv_[4];
#pragma unroll
        for (int i = 0; i < 4; i++) wv_[i] = wc1s[(ot + i) * ROWP + o];
#pragma unroll
        for (int j = 0; j < 4; j++) sv_[j] = wdk[o * ROWP + cb + j];
#pragma unroll
        for (int i = 0; i < 4; i++)
#pragma unroll
            for (int j = 0; j < 4; j++) a[i][j] += wv_[i] * sv_[j];
    }
#pragma unroll
    for (int i = 0; i < 4; i++)
#pragma unroll
        for (int j = 0; j < 4; j++) {
            int o2 = ot + i, c = cb + j;
            int tt = o2 >> 4, m = o2 & 15;
            int kt = c >> 5, q = (c >> 3) & 3, jj = c & 7;
            int ln = q * 16 + m;
            wA[(k * 8 + tt * 2 + kt) * 512 + ln * 8 + jj] = (short)f2bf(a[i][j]);
        }
}

// ---------------------------------------------------------------------------
// k_trans: enc [c][p] -> encP [p][c]
// ---------------------------------------------------------------------------
__global__ __launch_bounds__(256) void k_trans(
    const float* __restrict__ enc, float* __restrict__ encP)
{
    __shared__ float s[64 * 65];
    int t = threadIdx.x;
    int base = blockIdx.x * 64;
#pragma unroll
    for (int r = 0; r < 16; r++) {
        int idx = t + r * 256;
        int p = idx & 63, c = idx >> 6;
        s[p * 65 + c] = enc[c * HWSZ + base + p];
    }
    __syncthreads();
#pragma unroll
    for (int r = 0; r < 16; r++) {
        int idx = t + r * 256;
        int c = idx & 63, p = idx >> 6;
        encP[(base + p) * 64 + c] = s[p * 65 + c];
    }
}

// ---------------------------------------------------------------------------
// k_deform: MFMA deformable conv, K-split across waves for TLP.
// LDS kept under 20 KB so 8 blocks/CU (32 waves/CU) are resident:
// two-phase tree reduction with a 2-slot buffer (w2,w3 -> w0,w1; w1 -> w0).
// ---------------------------------------------------------------------------
#define REDW 20   // reduction row stride (floats): 80B, 16B-aligned

__global__ __launch_bounds__(256) void k_deform(
    const float* __restrict__ encP, const float* __restrict__ off,
    const float* __restrict__ msk, const short* __restrict__ wA,
    float* __restrict__ rev)
{
    __shared__ __align__(16) short sm[4][16 * SROW];   // 9216 B bounce
    __shared__ __align__(16) float red[2 * 64 * REDW]; // 10240 B reduction

    int t = threadIdx.x;
    int lane = t & 63, w = t >> 6;
    int b = blockIdx.x;
    int xcd = b & 7, blk = b >> 3;          // 288 strips per xcd band
    int gy  = xcd * 24 + blk / 12;
    int gx0 = (blk % 12) * 16;

    int sp = lane >> 2, g = lane & 3;
    int sgx  = gx0 + sp;
    int gp_s = gy * WW + sgx;
    int n = lane & 15, q = lane >> 4;
    short* smw = &sm[w][0];

    f32x4 acc[4];
#pragma unroll
    for (int ot = 0; ot < 4; ot++) acc[ot] = (f32x4){0.f, 0.f, 0.f, 0.f};

    int kstart = (w == 0) ? 0 : 13 + (w - 1) * 12;
    int kend   = (w == 0) ? 13 : kstart + 12;

    float dy = off[(2 * kstart) * HWSZ + gp_s];
    float dx = off[(2 * kstart + 1) * HWSZ + gp_s];
    float mm = msk[kstart * HWSZ + gp_s];

#pragma unroll 1
    for (int k = kstart; k < kend; k++) {
        int ky = k / 7, kx = k % 7;
        float y = (float)(gy  - 3 + ky) + dy;
        float x = (float)(sgx - 3 + kx) + dx;
        float y0f = floorf(y), x0f = floorf(x);
        float wy = y - y0f, wx = x - x0f;
        int iy0 = (int)y0f, ix0 = (int)x0f;
        int iy1 = iy0 + 1, ix1 = ix0 + 1;
        bool vy0 = (iy0 >= 0) & (iy0 < HH);
        bool vy1 = (iy1 >= 0) & (iy1 < HH);
        bool vx0 = (ix0 >= 0) & (ix0 < WW);
        bool vx1 = (ix1 >= 0) & (ix1 < WW);
        int iy0c = min(max(iy0, 0), HH - 1), iy1c = min(max(iy1, 0), HH - 1);
        int ix0c = min(max(ix0, 0), WW - 1), ix1c = min(max(ix1, 0), WW - 1);
        float a00 = (vy0 & vx0) ? (1.f - wy) * (1.f - wx) * mm : 0.f;
        float a01 = (vy0 & vx1) ? (1.f - wy) * wx * mm : 0.f;
        float a10 = (vy1 & vx0) ? wy * (1.f - wx) * mm : 0.f;
        float a11 = (vy1 & vx1) ? wy * wx * mm : 0.f;

        const float4* p00 = (const float4*)(encP + (iy0c * WW + ix0c) * 64 + g * 16);
        const float4* p01 = (const float4*)(encP + (iy0c * WW + ix1c) * 64 + g * 16);
        const float4* p10 = (const float4*)(encP + (iy1c * WW + ix0c) * 64 + g * 16);
        const float4* p11 = (const float4*)(encP + (iy1c * WW + ix1c) * 64 + g * 16);
        float4 c00[4], c01[4], c10[4], c11[4];
#pragma unroll
        for (int i = 0; i < 4; i++) {
            c00[i] = p00[i]; c01[i] = p01[i];
            c10[i] = p10[i]; c11[i] = p11[i];
        }

        // prefetch next-tap offsets
        float dyn = 0.f, dxn = 0.f, mmn = 0.f;
        if (k + 1 < kend) {
            dyn = off[(2 * k + 2) * HWSZ + gp_s];
            dxn = off[(2 * k + 3) * HWSZ + gp_s];
            mmn = msk[(k + 1) * HWSZ + gp_s];
        }

        // A-frag loads (L2-hot, independent of samples)
        s16x8 af[8];
#pragma unroll
        for (int f = 0; f < 8; f++)
            af[f] = *(const s16x8*)&wA[(k * 8 + f) * 512 + lane * 8];

        // blend + pack bf16 + wave-private LDS bounce
        unsigned pk[8];
#pragma unroll
        for (int i = 0; i < 4; i++) {
            float f0 = a00 * c00[i].x + a01 * c01[i].x + a10 * c10[i].x + a11 * c11[i].x;
            float f1 = a00 * c00[i].y + a01 * c01[i].y + a10 * c10[i].y + a11 * c11[i].y;
            float f2 = a00 * c00[i].z + a01 * c01[i].z + a10 * c10[i].z + a11 * c11[i].z;
            float f3 = a00 * c00[i].w + a01 * c01[i].w + a10 * c10[i].w + a11 * c11[i].w;
            pk[2 * i]     = pkbf(f0, f1);
            pk[2 * i + 1] = pkbf(f2, f3);
        }
        *(uint4*)&smw[sp * SROW + g * 16]     = make_uint4(pk[0], pk[1], pk[2], pk[3]);
        *(uint4*)&smw[sp * SROW + g * 16 + 8] = make_uint4(pk[4], pk[5], pk[6], pk[7]);

        s16x8 b0 = *(const s16x8*)&smw[n * SROW +  0 + q * 8];
        s16x8 b1 = *(const s16x8*)&smw[n * SROW + 32 + q * 8];

#pragma unroll
        for (int ot = 0; ot < 4; ot++) {
            acc[ot] = __builtin_amdgcn_mfma_f32_16x16x32_bf16(af[ot * 2],     b0, acc[ot], 0, 0, 0);
            acc[ot] = __builtin_amdgcn_mfma_f32_16x16x32_bf16(af[ot * 2 + 1], b1, acc[ot], 0, 0, 0);
        }

        dy = dyn; dx = dxn; mm = mmn;
    }

    // two-phase tree reduction (2-slot buffer keeps LDS < 20 KB)
    if (w >= 2) {
        float* rp = &red[((w - 2) * 64 + lane) * REDW];
#pragma unroll
        for (int ot = 0; ot < 4; ot++)
            *(float4*)&rp[ot * 4] = make_float4(acc[ot][0], acc[ot][1], acc[ot][2], acc[ot][3]);
    }
    __syncthreads();
    if (w < 2) {
        const float* rp = &red[(w * 64 + lane) * REDW];
#pragma unroll
        for (int ot = 0; ot < 4; ot++) {
            float4 v = *(const float4*)&rp[ot * 4];
            acc[ot][0] += v.x; acc[ot][1] += v.y;
            acc[ot][2] += v.z; acc[ot][3] += v.w;
        }
    }
    __syncthreads();
    if (w == 1) {
        float* rp = &red[lane * REDW];
#pragma unroll
        for (int ot = 0; ot < 4; ot++)
            *(float4*)&rp[ot * 4] = make_float4(acc[ot][0], acc[ot][1], acc[ot][2], acc[ot][3]);
    }
    __syncthreads();
    if (w == 0) {
        const float* rp = &red[lane * REDW];
#pragma unroll
        for (int ot = 0; ot < 4; ot++) {
            float4 v = *(const float4*)&rp[ot * 4];
            acc[ot][0] += v.x; acc[ot][1] += v.y;
            acc[ot][2] += v.z; acc[ot][3] += v.w;
        }
        int gp_m = gy * WW + gx0 + n;
#pragma unroll
        for (int ot = 0; ot < 4; ot++) {
            float4 rv = make_float4(acc[ot][0], acc[ot][1], acc[ot][2], acc[ot][3]);
            *(float4*)&rev[gp_m * 64 + ot * 16 + q * 4] = rv;
        }
    }
}

// ---------------------------------------------------------------------------
// k_fft: per 8x8 patch: proj_in via MFMA bf16, then circular conv (fp32).
// ---------------------------------------------------------------------------
__global__ __launch_bounds__(256) void k_fft(
    const float* __restrict__ encPg, const short* __restrict__ wpiA,
    const float* __restrict__ krT, float* __restrict__ e1)
{
    __shared__ __align__(16) short sbf[64 * SROW];   // bf16 enc [px][c]
    __shared__ __align__(16) float e0[64 * ROWP];    // fp32 [px][o]
    int t = threadIdx.x;
    int pbx = blockIdx.x % 24, pby = blockIdx.x / 24;
    int gx0 = pbx * 8, gy0 = pby * 8;

#pragma unroll
    for (int r = 0; r < 4; r++) {
        int idx = t + r * 256;
        int px = idx >> 4, g = idx & 15;
        int gy = gy0 + (px >> 3), gx = gx0 + (px & 7);
        float4 v = *(const float4*)&encPg[(gy * WW + gx) * 64 + g * 4];
        *(uint2*)&sbf[px * SROW + g * 4] = make_uint2(pkbf(v.x, v.y), pkbf(v.z, v.w));
    }
    __syncthreads();

    int lane = t & 63, w = t >> 6;
    int n = lane & 15, q = lane >> 4;
    s16x8 a0 = *(const s16x8*)&wpiA[(w * 2 + 0) * 512 + lane * 8];
    s16x8 a1 = *(const s16x8*)&wpiA[(w * 2 + 1) * 512 + lane * 8];
#pragma unroll
    for (int j = 0; j < 4; j++) {
        s16x8 b0 = *(const s16x8*)&sbf[(j * 16 + n) * SROW +  0 + q * 8];
        s16x8 b1 = *(const s16x8*)&sbf[(j * 16 + n) * SROW + 32 + q * 8];
        f32x4 acc = {0.f, 0.f, 0.f, 0.f};
        acc = __builtin_amdgcn_mfma_f32_16x16x32_bf16(a0, b0, acc, 0, 0, 0);
        acc = __builtin_amdgcn_mfma_f32_16x16x32_bf16(a1, b1, acc, 0, 0, 0);
#pragma unroll
        for (int r = 0; r < 4; r++)
            e0[(j * 16 + n) * ROWP + w * 16 + q * 4 + r] = acc[r];
    }
    __syncthreads();

    int o = t & 63;
    int yb = t >> 6;
#pragma unroll
    for (int yy = 0; yy < 2; yy++) {
        int y = yb + yy * 4;
        float outr[8];
#pragma unroll
        for (int x = 0; x < 8; x++) outr[x] = 0.f;
#pragma unroll
        for (int u = 0; u < 8; u++) {
            int ry = (y - u + 8) & 7;
            float row[8];
#pragma unroll
            for (int rx = 0; rx < 8; rx++)
                row[rx] = e0[(ry * 8 + rx) * ROWP + o];
#pragma unroll
            for (int v = 0; v < 8; v++) {
                float kv = krT[(u * 8 + v) * 64 + o];
#pragma unroll
                for (int x = 0; x < 8; x++)
                    outr[x] += kv * row[(x - v + 8) & 7];
            }
        }
        int gy = gy0 + y;
#pragma unroll
        for (int x = 0; x < 8; x++)
            e1[(gy * WW + gx0 + x) * 64 + o] = outr[x];
    }
}

// ---------------------------------------------------------------------------
// k_c3out: fused conv3x3(e1+rev) -> [.,dec] -> proj_out -> SimpleGate.
// Wave = 16x1 px strip; conv3 acc (C-layout regs) goes straight into the
// proj_out B-fragment LDS rows (no e3 round trip). Barrier-free.
// ---------------------------------------------------------------------------
__global__ __launch_bounds__(256) void k_c3out(
    const float* __restrict__ e1, const float* __restrict__ rev,
    const short* __restrict__ w2A, const float* __restrict__ dec,
    const short* __restrict__ wpoA, float* __restrict__ out)
{
    __shared__ __align__(16) short sm[4][54 * C3ROW];  // per-wave: 3 rows x 18 px
    int t = threadIdx.x;
    int lane = t & 63, w = t >> 6;
    int b = blockIdx.x;
    int xcd = b & 7, blk = b >> 3;
    int gy  = xcd * 24 + blk / 3;
    int gx0 = (blk % 3) * 64 + w * 16;
    short* smw = &sm[w][0];
    int n = lane & 15, q = lane >> 4;

    // stage halo: 54 rp x 16 float4-groups = 864 units over 64 lanes
    for (int r = 0; r < 14; r++) {
        int u = lane + r * 64;
        if (u < 864) {
            int rp = u >> 4, g = u & 15;
            int row = rp / 18, pxl = rp - row * 18;
            int gyy = gy + row - 1, gxx = gx0 + pxl - 1;
            float4 v = make_float4(0.f, 0.f, 0.f, 0.f);
            if (gyy >= 0 && gyy < HH && gxx >= 0 && gxx < WW) {
                int gp = (gyy * WW + gxx) * 64 + g * 4;
                float4 va = *(const float4*)&e1[gp];
                float4 vb = *(const float4*)&rev[gp];
                v.x = va.x + vb.x; v.y = va.y + vb.y;
                v.z = va.z + vb.z; v.w = va.w + vb.w;
            }
            *(uint2*)&smw[rp * C3ROW + g * 4] = make_uint2(pkbf(v.x, v.y), pkbf(v.z, v.w));
        }
    }

    f32x4 acc[4];
#pragma unroll
    for (int ot = 0; ot < 4; ot++) acc[ot] = (f32x4){0.f, 0.f, 0.f, 0.f};

#pragma unroll 1
    for (int tap = 0; tap < 9; tap++) {
        int dy = tap / 3, dx = tap - dy * 3;
        int rp = dy * 18 + n + dx;
        s16x8 b0 = *(const s16x8*)&smw[rp * C3ROW +  0 + q * 8];
        s16x8 b1 = *(const s16x8*)&smw[rp * C3ROW + 32 + q * 8];
#pragma unroll
        for (int ot = 0; ot < 4; ot++) {
            s16x8 a0 = *(const s16x8*)&w2A[(tap * 8 + ot * 2 + 0) * 512 + lane * 8];
            s16x8 a1 = *(const s16x8*)&w2A[(tap * 8 + ot * 2 + 1) * 512 + lane * 8];
            acc[ot] = __builtin_amdgcn_mfma_f32_16x16x32_bf16(a0, b0, acc[ot], 0, 0, 0);
            acc[ot] = __builtin_amdgcn_mfma_f32_16x16x32_bf16(a1, b1, acc[ot], 0, 0, 0);
        }
    }

    // ---- fused k_out: stage e3 (C-layout regs) + dec into B-frag rows ----
    // lane (q,n): pixel n, channels ot*16 + q*4 + r (consecutive r=0..3)
#pragma unroll
    for (int ot = 0; ot < 4; ot++) {
        unsigned lo = pkbf(acc[ot][0], acc[ot][1]);
        unsigned hi = pkbf(acc[ot][2], acc[ot][3]);
        *(uint2*)&smw[n * OROW + ot * 16 + q * 4] = make_uint2(lo, hi);
    }
    {
        int gp = gy * WW + gx0 + n;
        unsigned pk[8];
#pragma unroll
        for (int i = 0; i < 8; i++) {
            float va = dec[(q * 16 + 2 * i)     * HWSZ + gp];
            float vb = dec[(q * 16 + 2 * i + 1) * HWSZ + gp];
            pk[i] = pkbf(va, vb);
        }
        *(uint4*)&smw[n * OROW + 64 + q * 16]     = make_uint4(pk[0], pk[1], pk[2], pk[3]);
        *(uint4*)&smw[n * OROW + 64 + q * 16 + 8] = make_uint4(pk[4], pk[5], pk[6], pk[7]);
    }

    f32x4 go[8];
#pragma unroll
    for (int ot = 0; ot < 8; ot++) go[ot] = (f32x4){0.f, 0.f, 0.f, 0.f};

#pragma unroll 1
    for (int kt = 0; kt < 4; kt++) {
        s16x8 bb = *(const s16x8*)&smw[n * OROW + kt * 32 + q * 8];
#pragma unroll
        for (int ot = 0; ot < 8; ot++) {
            s16x8 aa = *(const s16x8*)&wpoA[(ot * 4 + kt) * 512 + lane * 8];
            go[ot] = __builtin_amdgcn_mfma_f32_16x16x32_bf16(aa, bb, go[ot], 0, 0, 0);
        }
    }

    int gp = gy * WW + gx0 + n;
#pragma unroll
    for (int ot = 0; ot < 4; ot++)
#pragma unroll
        for (int r = 0; r < 4; r++)
            out[(ot * 16 + q * 4 + r) * HWSZ + gp] = go[ot][r] * go[ot + 4][r];
}

// ---------------------------------------------------------------------------
extern "C" void kernel_launch(void* const* d_in, const int* in_sizes, int n_in,
                              void* d_out, int out_size, void* d_ws, size_t ws_size,
                              hipStream_t stream)
{
    const float* enc  = (const float*)d_in[0];
    const float* dec  = (const float*)d_in[1];
    const float* ioff = (const float*)d_in[2];
    const float* iwt  = (const float*)d_in[3];
    const float* wpi  = (const float*)d_in[4];
    const float* fw   = (const float*)d_in[5];
    const float* wpo  = (const float*)d_in[6];
    const float* wd   = (const float*)d_in[7];
    const float* wc1  = (const float*)d_in[8];
    const float* wc2  = (const float*)d_in[9];
    float* out = (float*)d_out;
    float* ws  = (float*)d_ws;

    float* krT  = ws;                       //    4096
    float* rev  = ws + 4096;                // 2359296  [px][64]
    float* e1   = ws + 2363392;             // 2359296  [px][64]
    float* encP = ws + 4722688;             // 2359296  [px][64]
    short* wA   = (short*)(ws + 7081984);   // 200704 bf16
    short* w2A  = (short*)(ws + 7182336);   //  36864 bf16
    short* wpoA = (short*)(ws + 7200768);   //  16384 bf16
    short* wpiA = (short*)(ws + 7208960);   //   4096 bf16

    hipLaunchKernelGGL(k_prep,   dim3(49),   dim3(256), 0, stream,
                       fw, wd, wc2, wc1, wpo, wpi, krT, wA, w2A, wpoA, wpiA);
    hipLaunchKernelGGL(k_trans,  dim3(576),  dim3(256), 0, stream, enc, encP);
    hipLaunchKernelGGL(k_deform, dim3(2304), dim3(256), 0, stream, encP, ioff, iwt, wA, rev);
    hipLaunchKernelGGL(k_fft,    dim3(576),  dim3(256), 0, stream, encP, wpiA, krT, e1);
    hipLaunchKernelGGL(k_c3out,  dim3(576),  dim3(256), 0, stream, e1, rev, w2A, dec, wpoA, out);
}